// Round 1
// baseline (1279.288 us; speedup 1.0000x reference)
//
#include <hip/hip_runtime.h>
#include <hip/hip_bf16.h>

#define DI __device__ __forceinline__

typedef float f32x4 __attribute__((ext_vector_type(4)));
typedef __bf16 bf16x8 __attribute__((ext_vector_type(8)));
using bf16_t = __hip_bfloat16;

// ---------------- async global->LDS (16B per lane) ----------------
DI void gload_lds16(const void* g, void* l) {
  __builtin_amdgcn_global_load_lds(
      (const __attribute__((address_space(1))) void*)g,
      (__attribute__((address_space(3))) void*)l, 16, 0, 0);
}

DI float rcpf(float x) { return __builtin_amdgcn_rcpf(x); }

// ---------------- 20-way weighted activation mixture ----------------
// ops order: softshrink, relu, identity, gelu(erf), elu, hardshrink, hardtanh,
// hardswish, selu, celu(=elu), leaky, logsigmoid, tanhshrink, softsign,
// softplus, tanh, sigmoid, hardsigmoid, silu, mish
DI float act_mix(float x, const float* aw, float lam) {
  const float ax  = fabsf(x);
  const float en  = __expf(-ax);        // e^{-|x|} in (0,1]
  const float en2 = en * en;            // e^{-2|x|}
  const float i1  = rcpf(1.0f + en);
  const float sig = (x >= 0.0f) ? i1 : en * i1;            // sigmoid
  const float th  = copysignf((1.0f - en2) * rcpf(1.0f + en2), x); // tanh
  const float l1p = __logf(1.0f + en);
  const float sp  = fmaxf(x, 0.0f) + l1p;                  // softplus
  const float lsg = fminf(x, 0.0f) - l1p;                  // logsigmoid
  const float q   = ((x >= 0.0f) ? en2 : 1.0f) * (i1 * i1);// e^{-2*softplus}
  const float mish = x * (1.0f - q) * rcpf(1.0f + q);
  // gelu exact via A&S 7.1.26 erf approx (|err|<=1.5e-7)
  const float u  = 0.7071067811865476f * x;
  const float au = fabsf(u);
  const float t  = rcpf(1.0f + 0.3275911f * au);
  float poly = fmaf(t, 1.061405429f, -1.453152027f);
  poly = fmaf(t, poly, 1.421413741f);
  poly = fmaf(t, poly, -0.284496736f);
  poly = fmaf(t, poly, 0.254829592f);
  poly *= t;
  const float erfa = 1.0f - poly * __expf(-u * u);
  const float gelu = 0.5f * x * (1.0f + copysignf(erfa, x));
  const float em1  = en - 1.0f;                            // e^x-1 for x<=0
  const float elu  = (x > 0.0f) ? x : em1;
  const float selu = (x > 0.0f) ? 1.0507009873554805f * x : 1.7580993408473766f * em1;
  const float relu = fmaxf(x, 0.0f);
  const float t6   = fminf(fmaxf(x + 3.0f, 0.0f), 6.0f) * 0.16666666666666666f;
  const float ssh  = (x > lam) ? (x - lam) : ((x < -lam) ? (x + lam) : 0.0f);
  const float hsh  = (ax > lam) ? x : 0.0f;
  const float htan = fminf(fmaxf(x, -1.0f), 1.0f);
  const float lky  = (x >= 0.0f) ? x : 0.01f * x;
  const float ssn  = x * rcpf(1.0f + ax);
  float r = aw[0] * ssh;
  r = fmaf(aw[1],  relu,   r);
  r = fmaf(aw[2],  x,      r);
  r = fmaf(aw[3],  gelu,   r);
  r = fmaf(aw[4],  elu,    r);
  r = fmaf(aw[5],  hsh,    r);
  r = fmaf(aw[6],  htan,   r);
  r = fmaf(aw[7],  x * t6, r);
  r = fmaf(aw[8],  selu,   r);
  r = fmaf(aw[9],  elu,    r);   // celu(alpha=1) == elu
  r = fmaf(aw[10], lky,    r);
  r = fmaf(aw[11], lsg,    r);
  r = fmaf(aw[12], x - th, r);
  r = fmaf(aw[13], ssn,    r);
  r = fmaf(aw[14], sp,     r);
  r = fmaf(aw[15], th,     r);
  r = fmaf(aw[16], sig,    r);
  r = fmaf(aw[17], t6,     r);
  r = fmaf(aw[18], x * sig, r);
  r = fmaf(aw[19], mish,   r);
  return r;
}

// ---------------- L pipeline: C = (X·X^T)*(1/s_in), frob^2 -> s_out ----------------
__global__ __launch_bounds__(256) void k_sq(const float* __restrict__ X, int K,
                                            float* __restrict__ C,
                                            const float* __restrict__ s_in,
                                            float* __restrict__ s_out) {
  __shared__ float Xa[32][33], Xb[32][33];
  const int tid = threadIdx.x;
  const int tx = tid & 15, ty = tid >> 4;
  const int i0 = blockIdx.x * 32, j0 = blockIdx.y * 32;
  float c00 = 0, c01 = 0, c10 = 0, c11 = 0;
  for (int kt = 0; kt < K; kt += 32) {
#pragma unroll
    for (int q = 0; q < 4; ++q) {
      int lin = tid + q * 256;
      int r = lin >> 5, c = lin & 31;
      Xa[r][c] = X[(i0 + r) * K + kt + c];
      Xb[r][c] = X[(j0 + r) * K + kt + c];
    }
    __syncthreads();
#pragma unroll
    for (int k = 0; k < 32; ++k) {
      float a0 = Xa[2 * ty][k], a1 = Xa[2 * ty + 1][k];
      float b0 = Xb[2 * tx][k], b1 = Xb[2 * tx + 1][k];
      c00 = fmaf(a0, b0, c00); c01 = fmaf(a0, b1, c01);
      c10 = fmaf(a1, b0, c10); c11 = fmaf(a1, b1, c11);
    }
    __syncthreads();
  }
  float s = s_in ? (1.0f / (*s_in)) : 1.0f;  // any positive scale works (eigvecs invariant)
  c00 *= s; c01 *= s; c10 *= s; c11 *= s;
  int r0 = i0 + 2 * ty, cc = j0 + 2 * tx;
  C[r0 * 512 + cc] = c00;       C[r0 * 512 + cc + 1] = c01;
  C[(r0 + 1) * 512 + cc] = c10; C[(r0 + 1) * 512 + cc + 1] = c11;
  float fro = c00 * c00 + c01 * c01 + c10 * c10 + c11 * c11;
  for (int off = 32; off; off >>= 1) fro += __shfl_down(fro, off, 64);
  if ((tid & 63) == 0) atomicAdd(s_out, fro);
}

// num = sum(A0 .* B) = tr(A0*B), den = tr(B)  ->  L = num/den (Rayleigh on A0)
__global__ void k_dot(const float* __restrict__ A0, const float* __restrict__ B,
                      float* num, float* den) {
  int i = blockIdx.x * 256 + threadIdx.x;
  float nv = 0.0f, dv = 0.0f;
  if (i < 512 * 512) {
    float b = B[i];
    nv = A0[i] * b;
    if ((i >> 9) == (i & 511)) dv = b;
  }
  for (int off = 32; off; off >>= 1) {
    nv += __shfl_down(nv, off, 64);
    dv += __shfl_down(dv, off, 64);
  }
  if ((threadIdx.x & 63) == 0) { atomicAdd(num, nv); atomicAdd(den, dv); }
}

// per-iteration params: [0..19]=softmax(alpha), [20]=c_{i+1}*bw0, [21]=1/L, [22]=lam
__global__ void k_setup(const float* __restrict__ alpha, const float* __restrict__ beta,
                        const float* __restrict__ num, const float* __restrict__ den,
                        float* __restrict__ params) {
  int t = threadIdx.x;
  if (t >= 10) return;
  float L = (*num) / (*den);
  float invL = 1.0f / L;
  float lam = 0.001f * invL;
  const float* a = alpha + t * 20;
  float mx = a[0];
  for (int k = 1; k < 20; ++k) mx = fmaxf(mx, a[k]);
  float e[20], s = 0.0f;
  for (int k = 0; k < 20; ++k) { e[k] = expf(a[k] - mx); s += e[k]; }
  float inv = 1.0f / s;
  float* P = params + t * 32;
  for (int k = 0; k < 20; ++k) P[k] = e[k] * inv;
  float b0 = beta[t * 2], b1 = beta[t * 2 + 1];
  float bm = fmaxf(b0, b1);
  float eb0 = expf(b0 - bm), eb1 = expf(b1 - bm);
  float bw0 = eb0 / (eb0 + eb1);
  P[20] = ((float)(t + 1) / (float)(t + 4)) * bw0;  // c_{i+1} * bw0_i
  P[21] = invL;
  P[22] = lam;
  P[23] = L;
}

__global__ void k_castw(const float* __restrict__ W, bf16_t* __restrict__ Wb,
                        bf16_t* __restrict__ Wt) {
  int i = blockIdx.x * 256 + threadIdx.x;
  if (i < 512 * 1024) {
    bf16_t v = __float2bfloat16(W[i]);
    Wb[i] = v;
    int n = i >> 10, h = i & 1023;
    Wt[h * 512 + n] = v;
  }
}

__global__ void k_negx(const float* __restrict__ x, bf16_t* __restrict__ out, int n) {
  int i = blockIdx.x * 256 + threadIdx.x;
  if (i < n) out[i] = __float2bfloat16(-x[i]);
}

// ---------------- GEMM1: Wzx[b][n] = sum_h zaux[b][h]*W[n][h] - x[b][n] ----------------
// A = zaux_bf16 [4096][1024], Bt = W_bf16 [512][1024]. BM=64 BN=128 BK=64, 4 waves.
__global__ __launch_bounds__(256) void k1_gemm(const bf16_t* __restrict__ A,
                                               const bf16_t* __restrict__ Bt,
                                               const float* __restrict__ x,
                                               bf16_t* __restrict__ Wzx) {
  constexpr int BK = 64;
  const int K = 1024;
  __shared__ __align__(16) unsigned short As[64 * BK];
  __shared__ __align__(16) unsigned short Bs[128 * BK];
  const int tid = threadIdx.x, lane = tid & 63, wave = tid >> 6;
  const int wm = wave >> 1, wn = wave & 1;
  const int m0 = blockIdx.x * 64, n0 = blockIdx.y * 128;
  const int r16 = lane & 15, kg = lane >> 4;
  f32x4 acc[2][4] = {};
  for (int kt = 0; kt < K; kt += BK) {
#pragma unroll
    for (int q = 0; q < 2; ++q) {
      int lin = (tid + q * 256) * 8;
      int r = lin >> 6, c = lin & 63;
      gload_lds16(A + (long)(m0 + r) * K + kt + c, (char*)As + lin * 2);
    }
#pragma unroll
    for (int q = 0; q < 4; ++q) {
      int lin = (tid + q * 256) * 8;
      int r = lin >> 6, c = lin & 63;
      gload_lds16(Bt + (long)(n0 + r) * K + kt + c, (char*)Bs + lin * 2);
    }
    __syncthreads();
#pragma unroll
    for (int kk = 0; kk < BK; kk += 32) {
      bf16x8 a[2], b[4];
#pragma unroll
      for (int f = 0; f < 2; ++f)
        a[f] = *(const bf16x8*)(As + (wm * 32 + f * 16 + r16) * BK + kk + kg * 8);
#pragma unroll
      for (int f = 0; f < 4; ++f)
        b[f] = *(const bf16x8*)(Bs + (wn * 64 + f * 16 + r16) * BK + kk + kg * 8);
#pragma unroll
      for (int i = 0; i < 2; ++i)
#pragma unroll
        for (int j = 0; j < 4; ++j)
          acc[i][j] = __builtin_amdgcn_mfma_f32_16x16x32_bf16(a[i], b[j], acc[i][j], 0, 0, 0);
    }
    __syncthreads();
  }
#pragma unroll
  for (int i = 0; i < 2; ++i)
#pragma unroll
    for (int j = 0; j < 4; ++j)
#pragma unroll
      for (int r = 0; r < 4; ++r) {
        int row = m0 + wm * 32 + i * 16 + (lane >> 4) * 4 + r;
        int col = n0 + wn * 64 + j * 16 + r16;
        int idx = row * 512 + col;
        Wzx[idx] = __float2bfloat16(acc[i][j][r] - x[idx]);
      }
}

// ---------------- GEMM2 + epilogue ----------------
// grad[b][h] = sum_n Wzx[b][n]*W[n][h]; zg = zaux - grad/L; zop = mix(zg);
// z_new = zop; zaux_next = zop + d_i*(zop - z_old).
template <bool FIRST, bool LAST, bool ZF32>
__global__ __launch_bounds__(256) void k2_gemm(const bf16_t* __restrict__ A,   // Wzx [4096][512]
                                               const bf16_t* __restrict__ Bt,  // Wt  [1024][512]
                                               float* zauxF,                   // [4096][1024] f32 (r/w)
                                               bf16_t* zauxB,                  // [4096][1024] bf16 (r/w)
                                               float* zio,                     // d_out: old z in, new z out
                                               const float* __restrict__ prm) {
  constexpr int BK = 64;
  const int K = 512, N = 1024;
  __shared__ __align__(16) unsigned short As[128 * BK];
  __shared__ __align__(16) unsigned short Bs[128 * BK];
  const int tid = threadIdx.x, lane = tid & 63, wave = tid >> 6;
  const int wm = wave >> 1, wn = wave & 1;
  const int m0 = blockIdx.x * 128, n0 = blockIdx.y * 128;
  const int r16 = lane & 15, kg = lane >> 4;
  f32x4 acc[4][4] = {};
  for (int kt = 0; kt < K; kt += BK) {
#pragma unroll
    for (int q = 0; q < 4; ++q) {
      int lin = (tid + q * 256) * 8;
      int r = lin >> 6, c = lin & 63;
      gload_lds16(A + (long)(m0 + r) * K + kt + c, (char*)As + lin * 2);
      gload_lds16(Bt + (long)(n0 + r) * K + kt + c, (char*)Bs + lin * 2);
    }
    __syncthreads();
#pragma unroll
    for (int kk = 0; kk < BK; kk += 32) {
      bf16x8 a[4], b[4];
#pragma unroll
      for (int f = 0; f < 4; ++f) {
        a[f] = *(const bf16x8*)(As + (wm * 64 + f * 16 + r16) * BK + kk + kg * 8);
        b[f] = *(const bf16x8*)(Bs + (wn * 64 + f * 16 + r16) * BK + kk + kg * 8);
      }
#pragma unroll
      for (int i = 0; i < 4; ++i)
#pragma unroll
        for (int j = 0; j < 4; ++j)
          acc[i][j] = __builtin_amdgcn_mfma_f32_16x16x32_bf16(a[i], b[j], acc[i][j], 0, 0, 0);
    }
    __syncthreads();
  }
  const float d_i = prm[20];
  const float invL = prm[21];
  const float lam = prm[22];
  float aw[20];
#pragma unroll
  for (int k = 0; k < 20; ++k) aw[k] = prm[k];
#pragma unroll
  for (int i = 0; i < 4; ++i)
#pragma unroll
    for (int j = 0; j < 4; ++j)
#pragma unroll
      for (int r = 0; r < 4; ++r) {
        int row = m0 + wm * 64 + i * 16 + (lane >> 4) * 4 + r;
        int col = n0 + wn * 64 + j * 16 + r16;
        long idx = (long)row * N + col;
        float grad = acc[i][j][r];
        float za = 0.0f, zold = 0.0f;
        if (!FIRST) {
          za = ZF32 ? zauxF[idx] : __bfloat162float(zauxB[idx]);
          zold = zio[idx];
        }
        float zg = fmaf(-grad, invL, za);
        float zop = act_mix(zg, aw, lam);
        zio[idx] = zop;
        if (!LAST) {
          float zx = fmaf(d_i, zop - zold, zop);
          if (ZF32) zauxF[idx] = zx;
          zauxB[idx] = __float2bfloat16(zx);
        }
      }
}

// ---------------- orchestration ----------------
extern "C" void kernel_launch(void* const* d_in, const int* in_sizes, int n_in,
                              void* d_out, int out_size, void* d_ws, size_t ws_size,
                              hipStream_t stream) {
  const float* x     = (const float*)d_in[0];
  const float* W     = (const float*)d_in[1];
  const float* alpha = (const float*)d_in[2];
  const float* beta  = (const float*)d_in[3];
  float* zout = (float*)d_out;

  char* ws = (char*)d_ws;
  const size_t MB = 1u << 20;
  float*  sc     = (float*)(ws);            // scalar slots (frob chain, num, den)
  float*  params = (float*)(ws + 2048);     // 10 x 32 floats
  float*  A0     = (float*)(ws + 8192);
  float*  Bp0    = (float*)(ws + 8192 + 1 * MB);
  float*  Bp1    = (float*)(ws + 8192 + 2 * MB);
  bf16_t* Wb     = (bf16_t*)(ws + 8192 + 3 * MB);
  bf16_t* Wt     = (bf16_t*)(ws + 8192 + 4 * MB);
  bf16_t* Wzx    = (bf16_t*)(ws + 8192 + 5 * MB);   // 4 MB
  bf16_t* zauxB  = (bf16_t*)(ws + 8192 + 9 * MB);   // 8 MB
  float*  zauxF  = (float*)(ws + 8192 + 17 * MB);   // 16 MB
  const bool useF32 = ws_size >= (size_t)(8192 + 33 * MB);

  hipMemsetAsync(ws, 0, 8192, stream);  // zero atomic accumulators

  k_castw<<<2048, 256, 0, stream>>>(W, Wb, Wt);

  // L: A0 = W*W^T, then 12 normalized squarings, then Rayleigh via traces
  k_sq<<<dim3(16, 16), 256, 0, stream>>>(W, 1024, A0, nullptr, &sc[0]);
  const float* src = A0;
  float* bufs[2] = {Bp0, Bp1};
  int pp = 0;
  for (int k = 0; k < 12; ++k) {
    k_sq<<<dim3(16, 16), 256, 0, stream>>>(src, 512, bufs[pp], &sc[k], &sc[k + 1]);
    src = bufs[pp];
    pp ^= 1;
  }
  k_dot<<<1024, 256, 0, stream>>>(A0, src, &sc[16], &sc[17]);
  k_setup<<<1, 64, 0, stream>>>(alpha, beta, &sc[16], &sc[17], params);

  // iter 0: z=0, zaux=0  ->  Wzx = -x
  k_negx<<<8192, 256, 0, stream>>>(x, Wzx, 4096 * 512);
  if (useF32)
    k2_gemm<true, false, true><<<dim3(32, 8), 256, 0, stream>>>(Wzx, Wt, zauxF, zauxB, zout, params);
  else
    k2_gemm<true, false, false><<<dim3(32, 8), 256, 0, stream>>>(Wzx, Wt, zauxF, zauxB, zout, params);

  for (int i = 1; i < 10; ++i) {
    k1_gemm<<<dim3(64, 4), 256, 0, stream>>>(zauxB, Wb, x, Wzx);
    const float* prm = params + i * 32;
    if (i < 9) {
      if (useF32)
        k2_gemm<false, false, true><<<dim3(32, 8), 256, 0, stream>>>(Wzx, Wt, zauxF, zauxB, zout, prm);
      else
        k2_gemm<false, false, false><<<dim3(32, 8), 256, 0, stream>>>(Wzx, Wt, zauxF, zauxB, zout, prm);
    } else {
      if (useF32)
        k2_gemm<false, true, true><<<dim3(32, 8), 256, 0, stream>>>(Wzx, Wt, zauxF, zauxB, zout, prm);
      else
        k2_gemm<false, true, false><<<dim3(32, 8), 256, 0, stream>>>(Wzx, Wt, zauxF, zauxB, zout, prm);
    }
  }
}

// Round 2
// 998.528 us; speedup vs baseline: 1.2812x; 1.2812x over previous
//
#include <hip/hip_runtime.h>
#include <hip/hip_bf16.h>

#define DI __device__ __forceinline__

typedef float f32x4 __attribute__((ext_vector_type(4)));
typedef __bf16 bf16x8 __attribute__((ext_vector_type(8)));
using bf16_t = __hip_bfloat16;

// ---------------- async global->LDS (16B per lane) ----------------
DI void gload_lds16(const void* g, void* l) {
  __builtin_amdgcn_global_load_lds(
      (const __attribute__((address_space(1))) void*)g,
      (__attribute__((address_space(3))) void*)l, 16, 0, 0);
}

DI float rcpf(float x) { return __builtin_amdgcn_rcpf(x); }

// ---------------- 20-way weighted activation mixture ----------------
DI float act_mix(float x, const float* aw, float lam) {
  const float ax  = fabsf(x);
  const float en  = __expf(-ax);        // e^{-|x|} in (0,1]
  const float en2 = en * en;            // e^{-2|x|}
  const float i1  = rcpf(1.0f + en);
  const float sig = (x >= 0.0f) ? i1 : en * i1;            // sigmoid
  const float th  = copysignf((1.0f - en2) * rcpf(1.0f + en2), x); // tanh
  const float l1p = __logf(1.0f + en);
  const float sp  = fmaxf(x, 0.0f) + l1p;                  // softplus
  const float lsg = fminf(x, 0.0f) - l1p;                  // logsigmoid
  const float q   = ((x >= 0.0f) ? en2 : 1.0f) * (i1 * i1);// e^{-2*softplus}
  const float mish = x * (1.0f - q) * rcpf(1.0f + q);
  // gelu exact via A&S 7.1.26 erf approx (|err|<=1.5e-7)
  const float u  = 0.7071067811865476f * x;
  const float au = fabsf(u);
  const float t  = rcpf(1.0f + 0.3275911f * au);
  float poly = fmaf(t, 1.061405429f, -1.453152027f);
  poly = fmaf(t, poly, 1.421413741f);
  poly = fmaf(t, poly, -0.284496736f);
  poly = fmaf(t, poly, 0.254829592f);
  poly *= t;
  const float erfa = 1.0f - poly * __expf(-u * u);
  const float gelu = 0.5f * x * (1.0f + copysignf(erfa, x));
  const float em1  = en - 1.0f;                            // e^x-1 for x<=0
  const float elu  = (x > 0.0f) ? x : em1;
  const float selu = (x > 0.0f) ? 1.0507009873554805f * x : 1.7580993408473766f * em1;
  const float relu = fmaxf(x, 0.0f);
  const float t6   = fminf(fmaxf(x + 3.0f, 0.0f), 6.0f) * 0.16666666666666666f;
  const float ssh  = (x > lam) ? (x - lam) : ((x < -lam) ? (x + lam) : 0.0f);
  const float hsh  = (ax > lam) ? x : 0.0f;
  const float htan = fminf(fmaxf(x, -1.0f), 1.0f);
  const float lky  = (x >= 0.0f) ? x : 0.01f * x;
  const float ssn  = x * rcpf(1.0f + ax);
  float r = aw[0] * ssh;
  r = fmaf(aw[1],  relu,   r);
  r = fmaf(aw[2],  x,      r);
  r = fmaf(aw[3],  gelu,   r);
  r = fmaf(aw[4],  elu,    r);
  r = fmaf(aw[5],  hsh,    r);
  r = fmaf(aw[6],  htan,   r);
  r = fmaf(aw[7],  x * t6, r);
  r = fmaf(aw[8],  selu,   r);
  r = fmaf(aw[9],  elu,    r);   // celu(alpha=1) == elu
  r = fmaf(aw[10], lky,    r);
  r = fmaf(aw[11], lsg,    r);
  r = fmaf(aw[12], x - th, r);
  r = fmaf(aw[13], ssn,    r);
  r = fmaf(aw[14], sp,     r);
  r = fmaf(aw[15], th,     r);
  r = fmaf(aw[16], sig,    r);
  r = fmaf(aw[17], t6,     r);
  r = fmaf(aw[18], x * sig, r);
  r = fmaf(aw[19], mish,   r);
  return r;
}

// ---------------- L pipeline ----------------
// C = (X·X^T)*scale where scale = 1/sum(pin[0..255]) (or 1 if pin==null).
// Writes per-block frobenius^2 partial to pout[bid]. NO atomics (round-1 lesson:
// 8k same-address atomicAdds = 106us at 13ns each, VALUBusy 0.4%).
__global__ __launch_bounds__(256) void k_sq(const float* __restrict__ X, int K,
                                            float* __restrict__ C,
                                            const float* __restrict__ pin,
                                            float* __restrict__ pout) {
  __shared__ float Xa[32][33], Xb[32][33];
  __shared__ float red[4];
  const int tid = threadIdx.x;
  const int tx = tid & 15, ty = tid >> 4;
  const int i0 = blockIdx.x * 32, j0 = blockIdx.y * 32;
  const int bid = blockIdx.y * gridDim.x + blockIdx.x;

  float s = 1.0f;
  if (pin) {                       // sum 256 L2-hot partials -> scale
    float v = pin[tid];
    for (int off = 32; off; off >>= 1) v += __shfl_down(v, off, 64);
    if ((tid & 63) == 0) red[tid >> 6] = v;
    __syncthreads();
    s = 1.0f / (red[0] + red[1] + red[2] + red[3]);
    __syncthreads();
  }

  float c00 = 0, c01 = 0, c10 = 0, c11 = 0;
  for (int kt = 0; kt < K; kt += 32) {
#pragma unroll
    for (int q = 0; q < 4; ++q) {
      int lin = tid + q * 256;
      int r = lin >> 5, c = lin & 31;
      Xa[r][c] = X[(i0 + r) * K + kt + c];
      Xb[r][c] = X[(j0 + r) * K + kt + c];
    }
    __syncthreads();
#pragma unroll
    for (int k = 0; k < 32; ++k) {
      float a0 = Xa[2 * ty][k], a1 = Xa[2 * ty + 1][k];
      float b0 = Xb[2 * tx][k], b1 = Xb[2 * tx + 1][k];
      c00 = fmaf(a0, b0, c00); c01 = fmaf(a0, b1, c01);
      c10 = fmaf(a1, b0, c10); c11 = fmaf(a1, b1, c11);
    }
    __syncthreads();
  }
  c00 *= s; c01 *= s; c10 *= s; c11 *= s;
  int r0 = i0 + 2 * ty, cc = j0 + 2 * tx;
  C[r0 * 512 + cc] = c00;       C[r0 * 512 + cc + 1] = c01;
  C[(r0 + 1) * 512 + cc] = c10; C[(r0 + 1) * 512 + cc + 1] = c11;
  float fro = c00 * c00 + c01 * c01 + c10 * c10 + c11 * c11;
  for (int off = 32; off; off >>= 1) fro += __shfl_down(fro, off, 64);
  if ((tid & 63) == 0) red[tid >> 6] = fro;
  __syncthreads();
  if (tid == 0) pout[bid] = red[0] + red[1] + red[2] + red[3];
}

// num_partial[bid] = sum_blk(A0 .* B), den_partial[bid] = sum_blk(diag(B))
__global__ __launch_bounds__(256) void k_dot(const float* __restrict__ A0,
                                             const float* __restrict__ B,
                                             float* __restrict__ numP,
                                             float* __restrict__ denP) {
  __shared__ float redn[4], redd[4];
  const int tid = threadIdx.x;
  const int idx4 = blockIdx.x * 256 + tid;          // 65536 float4s total
  const f32x4 a = ((const f32x4*)A0)[idx4];
  const f32x4 b = ((const f32x4*)B)[idx4];
  float nv = a[0]*b[0] + a[1]*b[1] + a[2]*b[2] + a[3]*b[3];
  float dv = 0.0f;
#pragma unroll
  for (int q = 0; q < 4; ++q) {
    int i = idx4 * 4 + q;
    if ((i >> 9) == (i & 511)) dv += b[q];
  }
  for (int off = 32; off; off >>= 1) {
    nv += __shfl_down(nv, off, 64);
    dv += __shfl_down(dv, off, 64);
  }
  if ((tid & 63) == 0) { redn[tid >> 6] = nv; redd[tid >> 6] = dv; }
  __syncthreads();
  if (tid == 0) {
    numP[blockIdx.x] = redn[0] + redn[1] + redn[2] + redn[3];
    denP[blockIdx.x] = redd[0] + redd[1] + redd[2] + redd[3];
  }
}

// Sums 256 num/den partials, then per-iteration params:
// [0..19]=softmax(alpha), [20]=c_{i+1}*bw0, [21]=1/L, [22]=lam
__global__ __launch_bounds__(256) void k_setup(const float* __restrict__ alpha,
                                               const float* __restrict__ beta,
                                               const float* __restrict__ numP,
                                               const float* __restrict__ denP,
                                               float* __restrict__ params) {
  __shared__ float redn[4], redd[4];
  __shared__ float Lsh;
  const int tid = threadIdx.x;
  float nv = numP[tid], dv = denP[tid];
  for (int off = 32; off; off >>= 1) {
    nv += __shfl_down(nv, off, 64);
    dv += __shfl_down(dv, off, 64);
  }
  if ((tid & 63) == 0) { redn[tid >> 6] = nv; redd[tid >> 6] = dv; }
  __syncthreads();
  if (tid == 0)
    Lsh = (redn[0] + redn[1] + redn[2] + redn[3]) /
          (redd[0] + redd[1] + redd[2] + redd[3]);
  __syncthreads();
  const int t = tid;
  if (t >= 10) return;
  float L = Lsh;
  float invL = 1.0f / L;
  float lam = 0.001f * invL;
  const float* a = alpha + t * 20;
  float mx = a[0];
  for (int k = 1; k < 20; ++k) mx = fmaxf(mx, a[k]);
  float e[20], ssum = 0.0f;
  for (int k = 0; k < 20; ++k) { e[k] = expf(a[k] - mx); ssum += e[k]; }
  float inv = 1.0f / ssum;
  float* P = params + t * 32;
  for (int k = 0; k < 20; ++k) P[k] = e[k] * inv;
  float b0 = beta[t * 2], b1 = beta[t * 2 + 1];
  float bm = fmaxf(b0, b1);
  float eb0 = expf(b0 - bm), eb1 = expf(b1 - bm);
  float bw0 = eb0 / (eb0 + eb1);
  P[20] = ((float)(t + 1) / (float)(t + 4)) * bw0;  // c_{i+1} * bw0_i
  P[21] = invL;
  P[22] = lam;
  P[23] = L;
}

__global__ void k_castw(const float* __restrict__ W, bf16_t* __restrict__ Wb,
                        bf16_t* __restrict__ Wt) {
  int i = blockIdx.x * 256 + threadIdx.x;
  if (i < 512 * 1024) {
    bf16_t v = __float2bfloat16(W[i]);
    Wb[i] = v;
    int n = i >> 10, h = i & 1023;
    Wt[h * 512 + n] = v;
  }
}

__global__ void k_negx(const float* __restrict__ x, bf16_t* __restrict__ out, int n) {
  int i = blockIdx.x * 256 + threadIdx.x;
  if (i < n) out[i] = __float2bfloat16(-x[i]);
}

// ---------------- GEMM1: Wzx[b][n] = sum_h zaux[b][h]*W[n][h] - x[b][n] ----------------
__global__ __launch_bounds__(256) void k1_gemm(const bf16_t* __restrict__ A,
                                               const bf16_t* __restrict__ Bt,
                                               const float* __restrict__ x,
                                               bf16_t* __restrict__ Wzx) {
  constexpr int BK = 64;
  const int K = 1024;
  __shared__ __align__(16) unsigned short As[64 * BK];
  __shared__ __align__(16) unsigned short Bs[128 * BK];
  const int tid = threadIdx.x, lane = tid & 63, wave = tid >> 6;
  const int wm = wave >> 1, wn = wave & 1;
  const int m0 = blockIdx.x * 64, n0 = blockIdx.y * 128;
  const int r16 = lane & 15, kg = lane >> 4;
  f32x4 acc[2][4] = {};
  for (int kt = 0; kt < K; kt += BK) {
#pragma unroll
    for (int q = 0; q < 2; ++q) {
      int lin = (tid + q * 256) * 8;
      int r = lin >> 6, c = lin & 63;
      gload_lds16(A + (long)(m0 + r) * K + kt + c, (char*)As + lin * 2);
    }
#pragma unroll
    for (int q = 0; q < 4; ++q) {
      int lin = (tid + q * 256) * 8;
      int r = lin >> 6, c = lin & 63;
      gload_lds16(Bt + (long)(n0 + r) * K + kt + c, (char*)Bs + lin * 2);
    }
    __syncthreads();
#pragma unroll
    for (int kk = 0; kk < BK; kk += 32) {
      bf16x8 a[2], b[4];
#pragma unroll
      for (int f = 0; f < 2; ++f)
        a[f] = *(const bf16x8*)(As + (wm * 32 + f * 16 + r16) * BK + kk + kg * 8);
#pragma unroll
      for (int f = 0; f < 4; ++f)
        b[f] = *(const bf16x8*)(Bs + (wn * 64 + f * 16 + r16) * BK + kk + kg * 8);
#pragma unroll
      for (int i = 0; i < 2; ++i)
#pragma unroll
        for (int j = 0; j < 4; ++j)
          acc[i][j] = __builtin_amdgcn_mfma_f32_16x16x32_bf16(a[i], b[j], acc[i][j], 0, 0, 0);
    }
    __syncthreads();
  }
#pragma unroll
  for (int i = 0; i < 2; ++i)
#pragma unroll
    for (int j = 0; j < 4; ++j)
#pragma unroll
      for (int r = 0; r < 4; ++r) {
        int row = m0 + wm * 32 + i * 16 + (lane >> 4) * 4 + r;
        int col = n0 + wn * 64 + j * 16 + r16;
        int idx = row * 512 + col;
        Wzx[idx] = __float2bfloat16(acc[i][j][r] - x[idx]);
      }
}

// ---------------- GEMM2 + epilogue ----------------
template <bool FIRST, bool LAST, bool ZF32>
__global__ __launch_bounds__(256) void k2_gemm(const bf16_t* __restrict__ A,   // Wzx [4096][512]
                                               const bf16_t* __restrict__ Bt,  // Wt  [1024][512]
                                               float* zauxF,                   // [4096][1024] f32
                                               bf16_t* zauxB,                  // [4096][1024] bf16
                                               float* zio,                     // d_out
                                               const float* __restrict__ prm) {
  constexpr int BK = 64;
  const int K = 512, N = 1024;
  __shared__ __align__(16) unsigned short As[128 * BK];
  __shared__ __align__(16) unsigned short Bs[128 * BK];
  const int tid = threadIdx.x, lane = tid & 63, wave = tid >> 6;
  const int wm = wave >> 1, wn = wave & 1;
  const int m0 = blockIdx.x * 128, n0 = blockIdx.y * 128;
  const int r16 = lane & 15, kg = lane >> 4;
  f32x4 acc[4][4] = {};
  for (int kt = 0; kt < K; kt += BK) {
#pragma unroll
    for (int q = 0; q < 4; ++q) {
      int lin = (tid + q * 256) * 8;
      int r = lin >> 6, c = lin & 63;
      gload_lds16(A + (long)(m0 + r) * K + kt + c, (char*)As + lin * 2);
      gload_lds16(Bt + (long)(n0 + r) * K + kt + c, (char*)Bs + lin * 2);
    }
    __syncthreads();
#pragma unroll
    for (int kk = 0; kk < BK; kk += 32) {
      bf16x8 a[4], b[4];
#pragma unroll
      for (int f = 0; f < 4; ++f) {
        a[f] = *(const bf16x8*)(As + (wm * 64 + f * 16 + r16) * BK + kk + kg * 8);
        b[f] = *(const bf16x8*)(Bs + (wn * 64 + f * 16 + r16) * BK + kk + kg * 8);
      }
#pragma unroll
      for (int i = 0; i < 4; ++i)
#pragma unroll
        for (int j = 0; j < 4; ++j)
          acc[i][j] = __builtin_amdgcn_mfma_f32_16x16x32_bf16(a[i], b[j], acc[i][j], 0, 0, 0);
    }
    __syncthreads();
  }
  const float d_i = prm[20];
  const float invL = prm[21];
  const float lam = prm[22];
  float aw[20];
#pragma unroll
  for (int k = 0; k < 20; ++k) aw[k] = prm[k];
#pragma unroll
  for (int i = 0; i < 4; ++i)
#pragma unroll
    for (int j = 0; j < 4; ++j)
#pragma unroll
      for (int r = 0; r < 4; ++r) {
        int row = m0 + wm * 64 + i * 16 + (lane >> 4) * 4 + r;
        int col = n0 + wn * 64 + j * 16 + r16;
        long idx = (long)row * N + col;
        float grad = acc[i][j][r];
        float za = 0.0f, zold = 0.0f;
        if (!FIRST) {
          za = ZF32 ? zauxF[idx] : __bfloat162float(zauxB[idx]);
          zold = zio[idx];
        }
        float zg = fmaf(-grad, invL, za);
        float zop = act_mix(zg, aw, lam);
        zio[idx] = zop;
        if (!LAST) {
          float zx = fmaf(d_i, zop - zold, zop);
          if (ZF32) zauxF[idx] = zx;
          zauxB[idx] = __float2bfloat16(zx);
        }
      }
}

// ---------------- orchestration ----------------
extern "C" void kernel_launch(void* const* d_in, const int* in_sizes, int n_in,
                              void* d_out, int out_size, void* d_ws, size_t ws_size,
                              hipStream_t stream) {
  const float* x     = (const float*)d_in[0];
  const float* W     = (const float*)d_in[1];
  const float* alpha = (const float*)d_in[2];
  const float* beta  = (const float*)d_in[3];
  float* zout = (float*)d_out;

  char* ws = (char*)d_ws;
  const size_t MB = 1u << 20;
  // header: 13 frob-partial arrays (256 f32 each), num/den partials, params
  float* pb[13];
  for (int k = 0; k < 13; ++k) pb[k] = (float*)(ws + (size_t)k * 1024);
  float* numP   = (float*)(ws + 13 * 1024);
  float* denP   = (float*)(ws + 14 * 1024);
  float* params = (float*)(ws + 15 * 1024);
  const size_t HDR = 32768;
  float*  A0    = (float*)(ws + HDR);
  float*  Bp0   = (float*)(ws + HDR + 1 * MB);
  float*  Bp1   = (float*)(ws + HDR + 2 * MB);
  bf16_t* Wb    = (bf16_t*)(ws + HDR + 3 * MB);
  bf16_t* Wt    = (bf16_t*)(ws + HDR + 4 * MB);
  bf16_t* Wzx   = (bf16_t*)(ws + HDR + 5 * MB);   // 4 MB
  bf16_t* zauxB = (bf16_t*)(ws + HDR + 9 * MB);   // 8 MB
  float*  zauxF = (float*)(ws + HDR + 17 * MB);   // 16 MB
  const bool useF32 = ws_size >= (size_t)(HDR + 33 * MB);

  k_castw<<<2048, 256, 0, stream>>>(W, Wb, Wt);

  // L: A0 = W*W^T, then 12 normalized squarings, then Rayleigh via traces
  k_sq<<<dim3(16, 16), 256, 0, stream>>>(W, 1024, A0, nullptr, pb[0]);
  const float* src = A0;
  float* bufs[2] = {Bp0, Bp1};
  int pp = 0;
  for (int k = 0; k < 12; ++k) {
    k_sq<<<dim3(16, 16), 256, 0, stream>>>(src, 512, bufs[pp], pb[k], pb[k + 1]);
    src = bufs[pp];
    pp ^= 1;
  }
  k_dot<<<256, 256, 0, stream>>>(A0, src, numP, denP);
  k_setup<<<1, 256, 0, stream>>>(alpha, beta, numP, denP, params);

  // iter 0: z=0, zaux=0  ->  Wzx = -x
  k_negx<<<8192, 256, 0, stream>>>(x, Wzx, 4096 * 512);
  if (useF32)
    k2_gemm<true, false, true><<<dim3(32, 8), 256, 0, stream>>>(Wzx, Wt, zauxF, zauxB, zout, params);
  else
    k2_gemm<true, false, false><<<dim3(32, 8), 256, 0, stream>>>(Wzx, Wt, zauxF, zauxB, zout, params);

  for (int i = 1; i < 10; ++i) {
    k1_gemm<<<dim3(64, 4), 256, 0, stream>>>(zauxB, Wb, x, Wzx);
    const float* prm = params + i * 32;
    if (i < 9) {
      if (useF32)
        k2_gemm<false, false, true><<<dim3(32, 8), 256, 0, stream>>>(Wzx, Wt, zauxF, zauxB, zout, prm);
      else
        k2_gemm<false, false, false><<<dim3(32, 8), 256, 0, stream>>>(Wzx, Wt, zauxF, zauxB, zout, prm);
    } else {
      if (useF32)
        k2_gemm<false, true, true><<<dim3(32, 8), 256, 0, stream>>>(Wzx, Wt, zauxF, zauxB, zout, prm);
      else
        k2_gemm<false, true, false><<<dim3(32, 8), 256, 0, stream>>>(Wzx, Wt, zauxF, zauxB, zout, prm);
    }
  }
}

// Round 3
// 660.173 us; speedup vs baseline: 1.9378x; 1.5125x over previous
//
#include <hip/hip_runtime.h>
#include <hip/hip_bf16.h>

#define DI __device__ __forceinline__

typedef float f32x4 __attribute__((ext_vector_type(4)));
typedef __bf16 bf16x8 __attribute__((ext_vector_type(8)));
using bf16_t = __hip_bfloat16;

// ---------------- async global->LDS (16B per lane) ----------------
DI void gload_lds16(const void* g, void* l) {
  __builtin_amdgcn_global_load_lds(
      (const __attribute__((address_space(1))) void*)g,
      (__attribute__((address_space(3))) void*)l, 16, 0, 0);
}

DI float rcpf(float x) { return __builtin_amdgcn_rcpf(x); }

// ---------------- 20-way weighted activation mixture ----------------
DI float act_mix(float x, const float* aw, float lam) {
  const float ax  = fabsf(x);
  const float en  = __expf(-ax);        // e^{-|x|} in (0,1]
  const float en2 = en * en;            // e^{-2|x|}
  const float i1  = rcpf(1.0f + en);
  const float sig = (x >= 0.0f) ? i1 : en * i1;            // sigmoid
  const float th  = copysignf((1.0f - en2) * rcpf(1.0f + en2), x); // tanh
  const float l1p = __logf(1.0f + en);
  const float sp  = fmaxf(x, 0.0f) + l1p;                  // softplus
  const float lsg = fminf(x, 0.0f) - l1p;                  // logsigmoid
  const float q   = ((x >= 0.0f) ? en2 : 1.0f) * (i1 * i1);// e^{-2*softplus}
  const float mish = x * (1.0f - q) * rcpf(1.0f + q);
  // gelu exact via A&S 7.1.26 erf approx (|err|<=1.5e-7)
  const float u  = 0.7071067811865476f * x;
  const float au = fabsf(u);
  const float t  = rcpf(1.0f + 0.3275911f * au);
  float poly = fmaf(t, 1.061405429f, -1.453152027f);
  poly = fmaf(t, poly, 1.421413741f);
  poly = fmaf(t, poly, -0.284496736f);
  poly = fmaf(t, poly, 0.254829592f);
  poly *= t;
  const float erfa = 1.0f - poly * __expf(-u * u);
  const float gelu = 0.5f * x * (1.0f + copysignf(erfa, x));
  const float em1  = en - 1.0f;                            // e^x-1 for x<=0
  const float elu  = (x > 0.0f) ? x : em1;
  const float selu = (x > 0.0f) ? 1.0507009873554805f * x : 1.7580993408473766f * em1;
  const float relu = fmaxf(x, 0.0f);
  const float t6   = fminf(fmaxf(x + 3.0f, 0.0f), 6.0f) * 0.16666666666666666f;
  const float ssh  = (x > lam) ? (x - lam) : ((x < -lam) ? (x + lam) : 0.0f);
  const float hsh  = (ax > lam) ? x : 0.0f;
  const float htan = fminf(fmaxf(x, -1.0f), 1.0f);
  const float lky  = (x >= 0.0f) ? x : 0.01f * x;
  const float ssn  = x * rcpf(1.0f + ax);
  float r = aw[0] * ssh;
  r = fmaf(aw[1],  relu,   r);
  r = fmaf(aw[2],  x,      r);
  r = fmaf(aw[3],  gelu,   r);
  r = fmaf(aw[4],  elu,    r);
  r = fmaf(aw[5],  hsh,    r);
  r = fmaf(aw[6],  htan,   r);
  r = fmaf(aw[7],  x * t6, r);
  r = fmaf(aw[8],  selu,   r);
  r = fmaf(aw[9],  elu,    r);   // celu(alpha=1) == elu
  r = fmaf(aw[10], lky,    r);
  r = fmaf(aw[11], lsg,    r);
  r = fmaf(aw[12], x - th, r);
  r = fmaf(aw[13], ssn,    r);
  r = fmaf(aw[14], sp,     r);
  r = fmaf(aw[15], th,     r);
  r = fmaf(aw[16], sig,    r);
  r = fmaf(aw[17], t6,     r);
  r = fmaf(aw[18], x * sig, r);
  r = fmaf(aw[19], mish,   r);
  return r;
}

// ---------------- L pipeline (unchanged from round 2) ----------------
__global__ __launch_bounds__(256) void k_sq(const float* __restrict__ X, int K,
                                            float* __restrict__ C,
                                            const float* __restrict__ pin,
                                            float* __restrict__ pout) {
  __shared__ float Xa[32][33], Xb[32][33];
  __shared__ float red[4];
  const int tid = threadIdx.x;
  const int tx = tid & 15, ty = tid >> 4;
  const int i0 = blockIdx.x * 32, j0 = blockIdx.y * 32;
  const int bid = blockIdx.y * gridDim.x + blockIdx.x;

  float s = 1.0f;
  if (pin) {
    float v = pin[tid];
    for (int off = 32; off; off >>= 1) v += __shfl_down(v, off, 64);
    if ((tid & 63) == 0) red[tid >> 6] = v;
    __syncthreads();
    s = 1.0f / (red[0] + red[1] + red[2] + red[3]);
    __syncthreads();
  }

  float c00 = 0, c01 = 0, c10 = 0, c11 = 0;
  for (int kt = 0; kt < K; kt += 32) {
#pragma unroll
    for (int q = 0; q < 4; ++q) {
      int lin = tid + q * 256;
      int r = lin >> 5, c = lin & 31;
      Xa[r][c] = X[(i0 + r) * K + kt + c];
      Xb[r][c] = X[(j0 + r) * K + kt + c];
    }
    __syncthreads();
#pragma unroll
    for (int k = 0; k < 32; ++k) {
      float a0 = Xa[2 * ty][k], a1 = Xa[2 * ty + 1][k];
      float b0 = Xb[2 * tx][k], b1 = Xb[2 * tx + 1][k];
      c00 = fmaf(a0, b0, c00); c01 = fmaf(a0, b1, c01);
      c10 = fmaf(a1, b0, c10); c11 = fmaf(a1, b1, c11);
    }
    __syncthreads();
  }
  c00 *= s; c01 *= s; c10 *= s; c11 *= s;
  int r0 = i0 + 2 * ty, cc = j0 + 2 * tx;
  C[r0 * 512 + cc] = c00;       C[r0 * 512 + cc + 1] = c01;
  C[(r0 + 1) * 512 + cc] = c10; C[(r0 + 1) * 512 + cc + 1] = c11;
  float fro = c00 * c00 + c01 * c01 + c10 * c10 + c11 * c11;
  for (int off = 32; off; off >>= 1) fro += __shfl_down(fro, off, 64);
  if ((tid & 63) == 0) red[tid >> 6] = fro;
  __syncthreads();
  if (tid == 0) pout[bid] = red[0] + red[1] + red[2] + red[3];
}

__global__ __launch_bounds__(256) void k_dot(const float* __restrict__ A0,
                                             const float* __restrict__ B,
                                             float* __restrict__ numP,
                                             float* __restrict__ denP) {
  __shared__ float redn[4], redd[4];
  const int tid = threadIdx.x;
  const int idx4 = blockIdx.x * 256 + tid;
  const f32x4 a = ((const f32x4*)A0)[idx4];
  const f32x4 b = ((const f32x4*)B)[idx4];
  float nv = a[0]*b[0] + a[1]*b[1] + a[2]*b[2] + a[3]*b[3];
  float dv = 0.0f;
#pragma unroll
  for (int q = 0; q < 4; ++q) {
    int i = idx4 * 4 + q;
    if ((i >> 9) == (i & 511)) dv += b[q];
  }
  for (int off = 32; off; off >>= 1) {
    nv += __shfl_down(nv, off, 64);
    dv += __shfl_down(dv, off, 64);
  }
  if ((tid & 63) == 0) { redn[tid >> 6] = nv; redd[tid >> 6] = dv; }
  __syncthreads();
  if (tid == 0) {
    numP[blockIdx.x] = redn[0] + redn[1] + redn[2] + redn[3];
    denP[blockIdx.x] = redd[0] + redd[1] + redd[2] + redd[3];
  }
}

__global__ __launch_bounds__(256) void k_setup(const float* __restrict__ alpha,
                                               const float* __restrict__ beta,
                                               const float* __restrict__ numP,
                                               const float* __restrict__ denP,
                                               float* __restrict__ params) {
  __shared__ float redn[4], redd[4];
  __shared__ float Lsh;
  const int tid = threadIdx.x;
  float nv = numP[tid], dv = denP[tid];
  for (int off = 32; off; off >>= 1) {
    nv += __shfl_down(nv, off, 64);
    dv += __shfl_down(dv, off, 64);
  }
  if ((tid & 63) == 0) { redn[tid >> 6] = nv; redd[tid >> 6] = dv; }
  __syncthreads();
  if (tid == 0)
    Lsh = (redn[0] + redn[1] + redn[2] + redn[3]) /
          (redd[0] + redd[1] + redd[2] + redd[3]);
  __syncthreads();
  const int t = tid;
  if (t >= 10) return;
  float L = Lsh;
  float invL = 1.0f / L;
  float lam = 0.001f * invL;
  const float* a = alpha + t * 20;
  float mx = a[0];
  for (int k = 1; k < 20; ++k) mx = fmaxf(mx, a[k]);
  float e[20], ssum = 0.0f;
  for (int k = 0; k < 20; ++k) { e[k] = expf(a[k] - mx); ssum += e[k]; }
  float inv = 1.0f / ssum;
  float* P = params + t * 32;
  for (int k = 0; k < 20; ++k) P[k] = e[k] * inv;
  float b0 = beta[t * 2], b1 = beta[t * 2 + 1];
  float bm = fmaxf(b0, b1);
  float eb0 = expf(b0 - bm), eb1 = expf(b1 - bm);
  float bw0 = eb0 / (eb0 + eb1);
  P[20] = ((float)(t + 1) / (float)(t + 4)) * bw0;  // c_{i+1} * bw0_i
  P[21] = invL;
  P[22] = lam;
  P[23] = L;
}

__global__ void k_castw(const float* __restrict__ W, bf16_t* __restrict__ Wb,
                        bf16_t* __restrict__ Wt) {
  int i = blockIdx.x * 256 + threadIdx.x;
  if (i < 512 * 1024) {
    bf16_t v = __float2bfloat16(W[i]);
    Wb[i] = v;
    int n = i >> 10, h = i & 1023;
    Wt[h * 512 + n] = v;
  }
}

__global__ void k_negx(const float* __restrict__ x, bf16_t* __restrict__ out, int n) {
  int i = blockIdx.x * 256 + threadIdx.x;
  if (i < n) out[i] = __float2bfloat16(-x[i]);
}

// ================= 64x64-tile MFMA GEMMs, XOR-swizzled LDS =================
// LDS tile: 64 rows x 64 cols bf16 (8KB). Granule = 8 bf16 = 16B.
// LDS slot (row, g) holds global granule g ^ (row&7)  [involution].
// Stage: linear LDS dest (gload_lds requirement), inverse-permuted global src.
// Read: elem_off = row*64 + ((kk + kg*8) ^ ((row&7)*8)).  Fixes the 16-way
// bank conflict from the 128B row stride (round-2: SQ_LDS_BANK_CONFLICT=1.57M).

// ---------------- GEMM1: Wzx[b][n] = sum_h zaux[b][h]*W[n][h] - x[b][n] ----
// A = zauxB [4096][1024], Bt = Wb [512][1024]. Grid 512 (64 m x 8 n), 4 waves.
__global__ __launch_bounds__(256) void k1_gemm(const bf16_t* __restrict__ A,
                                               const bf16_t* __restrict__ Bt,
                                               const float* __restrict__ x,
                                               bf16_t* __restrict__ Wzx) {
  const int K = 1024;
  __shared__ __align__(16) unsigned short As[64 * 64];
  __shared__ __align__(16) unsigned short Bs[64 * 64];
  const int tid = threadIdx.x, lane = tid & 63, wave = tid >> 6;
  const int wm = wave >> 1, wn = wave & 1;
  int bid = blockIdx.x;
  int swz = (bid & 7) * 64 + (bid >> 3);          // XCD swizzle (512 % 8 == 0)
  const int m0 = (swz & 63) * 64, n0 = (swz >> 6) * 64;
  const int r16 = lane & 15, kg = lane >> 4;
  f32x4 acc[2][2] = {};
  for (int kt = 0; kt < K; kt += 64) {
#pragma unroll
    for (int q = 0; q < 2; ++q) {
      int lin = (tid + q * 256) * 8;
      int row = lin >> 6;
      int col = ((((lin >> 3) & 7) ^ (row & 7)) << 3);   // inverse-swizzled src
      gload_lds16(A + (long)(m0 + row) * K + kt + col, (char*)As + lin * 2);
      gload_lds16(Bt + (long)(n0 + row) * K + kt + col, (char*)Bs + lin * 2);
    }
    __syncthreads();
#pragma unroll
    for (int kk = 0; kk < 64; kk += 32) {
      bf16x8 a[2], b[2];
#pragma unroll
      for (int f = 0; f < 2; ++f) {
        int ra = wm * 32 + f * 16 + r16;
        int rb = wn * 32 + f * 16 + r16;
        a[f] = *(const bf16x8*)(As + ra * 64 + ((kk + kg * 8) ^ ((ra & 7) * 8)));
        b[f] = *(const bf16x8*)(Bs + rb * 64 + ((kk + kg * 8) ^ ((rb & 7) * 8)));
      }
#pragma unroll
      for (int i = 0; i < 2; ++i)
#pragma unroll
        for (int j = 0; j < 2; ++j)
          acc[i][j] = __builtin_amdgcn_mfma_f32_16x16x32_bf16(a[i], b[j], acc[i][j], 0, 0, 0);
    }
    __syncthreads();
  }
#pragma unroll
  for (int i = 0; i < 2; ++i)
#pragma unroll
    for (int j = 0; j < 2; ++j)
#pragma unroll
      for (int r = 0; r < 4; ++r) {
        int row = m0 + wm * 32 + i * 16 + (lane >> 4) * 4 + r;
        int col = n0 + wn * 32 + j * 16 + r16;
        int idx = row * 512 + col;
        Wzx[idx] = __float2bfloat16(acc[i][j][r] - x[idx]);
      }
}

// ---------------- GEMM2 + epilogue --------------------------------------
// grad[b][h] = sum_n Wzx[b][n]*W[n][h]; zg = zaux - grad/L; zop = mix(zg);
// z_new = zop; zaux_next = zop + d_i*(zop - z_old).
// A = Wzx [4096][512], Bt = Wt [1024][512]. Grid 1024 (64 m x 16 n), 4 waves.
template <bool FIRST, bool LAST>
__global__ __launch_bounds__(256) void k2_gemm(const bf16_t* __restrict__ A,
                                               const bf16_t* __restrict__ Bt,
                                               bf16_t* zauxB,                 // [4096][1024]
                                               float* zio,                    // d_out
                                               const float* __restrict__ prm) {
  const int K = 512, N = 1024;
  __shared__ __align__(16) unsigned short As[64 * 64];
  __shared__ __align__(16) unsigned short Bs[64 * 64];
  const int tid = threadIdx.x, lane = tid & 63, wave = tid >> 6;
  const int wm = wave >> 1, wn = wave & 1;
  int bid = blockIdx.x;
  int swz = (bid & 7) * 128 + (bid >> 3);         // XCD swizzle (1024 % 8 == 0)
  const int m0 = (swz & 63) * 64, n0 = (swz >> 6) * 64;
  const int r16 = lane & 15, kg = lane >> 4;
  f32x4 acc[2][2] = {};
  for (int kt = 0; kt < K; kt += 64) {
#pragma unroll
    for (int q = 0; q < 2; ++q) {
      int lin = (tid + q * 256) * 8;
      int row = lin >> 6;
      int col = ((((lin >> 3) & 7) ^ (row & 7)) << 3);
      gload_lds16(A + (long)(m0 + row) * K + kt + col, (char*)As + lin * 2);
      gload_lds16(Bt + (long)(n0 + row) * K + kt + col, (char*)Bs + lin * 2);
    }
    __syncthreads();
#pragma unroll
    for (int kk = 0; kk < 64; kk += 32) {
      bf16x8 a[2], b[2];
#pragma unroll
      for (int f = 0; f < 2; ++f) {
        int ra = wm * 32 + f * 16 + r16;
        int rb = wn * 32 + f * 16 + r16;
        a[f] = *(const bf16x8*)(As + ra * 64 + ((kk + kg * 8) ^ ((ra & 7) * 8)));
        b[f] = *(const bf16x8*)(Bs + rb * 64 + ((kk + kg * 8) ^ ((rb & 7) * 8)));
      }
#pragma unroll
      for (int i = 0; i < 2; ++i)
#pragma unroll
        for (int j = 0; j < 2; ++j)
          acc[i][j] = __builtin_amdgcn_mfma_f32_16x16x32_bf16(a[i], b[j], acc[i][j], 0, 0, 0);
    }
    __syncthreads();
  }
  const float d_i = prm[20];
  const float invL = prm[21];
  const float lam = prm[22];
  float aw[20];
#pragma unroll
  for (int k = 0; k < 20; ++k) aw[k] = prm[k];
#pragma unroll
  for (int i = 0; i < 2; ++i)
#pragma unroll
    for (int j = 0; j < 2; ++j)
#pragma unroll
      for (int r = 0; r < 4; ++r) {
        int row = m0 + wm * 32 + i * 16 + (lane >> 4) * 4 + r;
        int col = n0 + wn * 32 + j * 16 + r16;
        long idx = (long)row * N + col;
        float grad = acc[i][j][r];
        float za = 0.0f, zold = 0.0f;
        if (!FIRST) {
          za = __bfloat162float(zauxB[idx]);
          zold = zio[idx];
        }
        float zg = fmaf(-grad, invL, za);
        float zop = act_mix(zg, aw, lam);
        zio[idx] = zop;
        if (!LAST) {
          float zx = fmaf(d_i, zop - zold, zop);
          zauxB[idx] = __float2bfloat16(zx);
        }
      }
}

// ---------------- orchestration ----------------
extern "C" void kernel_launch(void* const* d_in, const int* in_sizes, int n_in,
                              void* d_out, int out_size, void* d_ws, size_t ws_size,
                              hipStream_t stream) {
  const float* x     = (const float*)d_in[0];
  const float* W     = (const float*)d_in[1];
  const float* alpha = (const float*)d_in[2];
  const float* beta  = (const float*)d_in[3];
  float* zout = (float*)d_out;

  char* ws = (char*)d_ws;
  const size_t MB = 1u << 20;
  float* pb[13];
  for (int k = 0; k < 13; ++k) pb[k] = (float*)(ws + (size_t)k * 1024);
  float* numP   = (float*)(ws + 13 * 1024);
  float* denP   = (float*)(ws + 14 * 1024);
  float* params = (float*)(ws + 15 * 1024);
  const size_t HDR = 32768;
  float*  A0    = (float*)(ws + HDR);
  float*  Bp0   = (float*)(ws + HDR + 1 * MB);
  float*  Bp1   = (float*)(ws + HDR + 2 * MB);
  bf16_t* Wb    = (bf16_t*)(ws + HDR + 3 * MB);
  bf16_t* Wt    = (bf16_t*)(ws + HDR + 4 * MB);
  bf16_t* Wzx   = (bf16_t*)(ws + HDR + 5 * MB);   // 4 MB
  bf16_t* zauxB = (bf16_t*)(ws + HDR + 9 * MB);   // 8 MB  (total 17MB: proven fit)

  k_castw<<<2048, 256, 0, stream>>>(W, Wb, Wt);

  // L: A0 = W*W^T, then 12 normalized squarings, then Rayleigh via traces
  k_sq<<<dim3(16, 16), 256, 0, stream>>>(W, 1024, A0, nullptr, pb[0]);
  const float* src = A0;
  float* bufs[2] = {Bp0, Bp1};
  int pp = 0;
  for (int k = 0; k < 12; ++k) {
    k_sq<<<dim3(16, 16), 256, 0, stream>>>(src, 512, bufs[pp], pb[k], pb[k + 1]);
    src = bufs[pp];
    pp ^= 1;
  }
  k_dot<<<256, 256, 0, stream>>>(A0, src, numP, denP);
  k_setup<<<1, 256, 0, stream>>>(alpha, beta, numP, denP, params);

  // iter 0: z=0, zaux=0  ->  Wzx = -x
  k_negx<<<8192, 256, 0, stream>>>(x, Wzx, 4096 * 512);
  k2_gemm<true, false><<<1024, 256, 0, stream>>>(Wzx, Wt, zauxB, zout, params);

  for (int i = 1; i < 10; ++i) {
    k1_gemm<<<512, 256, 0, stream>>>(zauxB, Wb, x, Wzx);
    const float* prm = params + i * 32;
    if (i < 9)
      k2_gemm<false, false><<<1024, 256, 0, stream>>>(Wzx, Wt, zauxB, zout, prm);
    else
      k2_gemm<false, true><<<1024, 256, 0, stream>>>(Wzx, Wt, zauxB, zout, prm);
  }
}

// Round 4
// 543.346 us; speedup vs baseline: 2.3545x; 1.2150x over previous
//
#include <hip/hip_runtime.h>
#include <hip/hip_bf16.h>

#define DI __device__ __forceinline__

typedef float f32x4 __attribute__((ext_vector_type(4)));
typedef __bf16 bf16x8 __attribute__((ext_vector_type(8)));
using bf16_t = __hip_bfloat16;

// ---------------- async global->LDS (16B per lane) ----------------
DI void gload_lds16(const void* g, void* l) {
  __builtin_amdgcn_global_load_lds(
      (const __attribute__((address_space(1))) void*)g,
      (__attribute__((address_space(3))) void*)l, 16, 0, 0);
}

DI float rcpf(float x) { return __builtin_amdgcn_rcpf(x); }

// ---------------- 20-way weighted activation mixture ----------------
DI float act_mix(float x, const float* aw, float lam) {
  const float ax  = fabsf(x);
  const float en  = __expf(-ax);        // e^{-|x|} in (0,1]
  const float en2 = en * en;            // e^{-2|x|}
  const float i1  = rcpf(1.0f + en);
  const float sig = (x >= 0.0f) ? i1 : en * i1;            // sigmoid
  const float th  = copysignf((1.0f - en2) * rcpf(1.0f + en2), x); // tanh
  const float l1p = __logf(1.0f + en);
  const float sp  = fmaxf(x, 0.0f) + l1p;                  // softplus
  const float lsg = fminf(x, 0.0f) - l1p;                  // logsigmoid
  const float q   = ((x >= 0.0f) ? en2 : 1.0f) * (i1 * i1);// e^{-2*softplus}
  const float mish = x * (1.0f - q) * rcpf(1.0f + q);
  // gelu exact via A&S 7.1.26 erf approx (|err|<=1.5e-7)
  const float u  = 0.7071067811865476f * x;
  const float au = fabsf(u);
  const float t  = rcpf(1.0f + 0.3275911f * au);
  float poly = fmaf(t, 1.061405429f, -1.453152027f);
  poly = fmaf(t, poly, 1.421413741f);
  poly = fmaf(t, poly, -0.284496736f);
  poly = fmaf(t, poly, 0.254829592f);
  poly *= t;
  const float erfa = 1.0f - poly * __expf(-u * u);
  const float gelu = 0.5f * x * (1.0f + copysignf(erfa, x));
  const float em1  = en - 1.0f;                            // e^x-1 for x<=0
  const float elu  = (x > 0.0f) ? x : em1;
  const float selu = (x > 0.0f) ? 1.0507009873554805f * x : 1.7580993408473766f * em1;
  const float relu = fmaxf(x, 0.0f);
  const float t6   = fminf(fmaxf(x + 3.0f, 0.0f), 6.0f) * 0.16666666666666666f;
  const float ssh  = (x > lam) ? (x - lam) : ((x < -lam) ? (x + lam) : 0.0f);
  const float hsh  = (ax > lam) ? x : 0.0f;
  const float htan = fminf(fmaxf(x, -1.0f), 1.0f);
  const float lky  = (x >= 0.0f) ? x : 0.01f * x;
  const float ssn  = x * rcpf(1.0f + ax);
  float r = aw[0] * ssh;
  r = fmaf(aw[1],  relu,   r);
  r = fmaf(aw[2],  x,      r);
  r = fmaf(aw[3],  gelu,   r);
  r = fmaf(aw[4],  elu,    r);
  r = fmaf(aw[5],  hsh,    r);
  r = fmaf(aw[6],  htan,   r);
  r = fmaf(aw[7],  x * t6, r);
  r = fmaf(aw[8],  selu,   r);
  r = fmaf(aw[9],  elu,    r);   // celu(alpha=1) == elu
  r = fmaf(aw[10], lky,    r);
  r = fmaf(aw[11], lsg,    r);
  r = fmaf(aw[12], x - th, r);
  r = fmaf(aw[13], ssn,    r);
  r = fmaf(aw[14], sp,     r);
  r = fmaf(aw[15], th,     r);
  r = fmaf(aw[16], sig,    r);
  r = fmaf(aw[17], t6,     r);
  r = fmaf(aw[18], x * sig, r);
  r = fmaf(aw[19], mish,   r);
  return r;
}

// ---------------- casts ----------------
// W [512][1024] f32 -> Whi/Wlo (hi/lo bf16 split, row-major), Wt (bf16 W^T)
__global__ void k_cast(const float* __restrict__ W, bf16_t* __restrict__ Whi,
                       bf16_t* __restrict__ Wlo, bf16_t* __restrict__ Wt) {
  int i = blockIdx.x * 256 + threadIdx.x;
  if (i < 512 * 1024) {
    float w = W[i];
    bf16_t h = __float2bfloat16(w);
    Whi[i] = h;
    Wlo[i] = __float2bfloat16(w - __bfloat162float(h));
    int n = i >> 10, hc = i & 1023;
    Wt[hc * 512 + n] = h;
  }
}

// x f32 -> xb bf16 (for k1 epilogue) and Wzx0 = bf16(-x) (iter-0 input to k2)
__global__ void k_prep(const float* __restrict__ x, bf16_t* __restrict__ xb,
                       bf16_t* __restrict__ Wzx) {
  int i = blockIdx.x * 256 + threadIdx.x;
  if (i < 4096 * 512) {
    float v = x[i];
    xb[i] = __float2bfloat16(v);
    Wzx[i] = __float2bfloat16(-v);
  }
}

// ---------------- L pipeline: MFMA hi/lo squaring ----------------
// C = scale*(X·X^T) with X given as hi/lo bf16; X·X^T ≈ hi·hi^T + hi·lo^T + lo·hi^T
// (lolo term ~1e-5 relative, dropped). scale = 1/sum(pin) (fro^2 of X).
// Output: hi/lo bf16 split of C (+ f32 C when WF32). Per-block fro^2 -> pout.
// 32x32 out tile, 4 waves (2x2 of 16x16), BK=64, double-buffered swizzled LDS.
template <int KDIM, bool FIRST, bool WF32>
__global__ __launch_bounds__(256) void k_sqm(
    const bf16_t* __restrict__ Xhi, const bf16_t* __restrict__ Xlo,
    bf16_t* __restrict__ Chi, bf16_t* __restrict__ Clo,
    float* __restrict__ Cf,
    const float* __restrict__ pin, float* __restrict__ pout) {
  __shared__ __align__(16) unsigned short Ah[2][32 * 64], Al[2][32 * 64],
                                          Bh[2][32 * 64], Bl[2][32 * 64];
  __shared__ float red[4];
  const int tid = threadIdx.x, lane = tid & 63, wave = tid >> 6;
  const int wm = wave >> 1, wn = wave & 1;
  const int i0 = blockIdx.x * 32, j0 = blockIdx.y * 32;
  const int bid = blockIdx.y * gridDim.x + blockIdx.x;
  const int r16 = lane & 15, kg = lane >> 4;

  float s = 1.0f;
  if constexpr (!FIRST) {
    float v = pin[tid];
    for (int off = 32; off; off >>= 1) v += __shfl_down(v, off, 64);
    if ((tid & 63) == 0) red[tid >> 6] = v;
    __syncthreads();
    s = 1.0f / (red[0] + red[1] + red[2] + red[3]);
    __syncthreads();
  }

  const int row = tid >> 3;                         // 0..31
  const int srcc = (((tid & 7) ^ (row & 7)) << 3);  // inverse-swizzled src col
  const long abase = (long)(i0 + row) * KDIM + srcc;
  const long bbase = (long)(j0 + row) * KDIM + srcc;
  const int ldst = tid * 8;                         // elements (16B/lane)

  auto stage = [&](int buf, int kt) {
    gload_lds16(Xhi + abase + kt, &Ah[buf][ldst]);
    gload_lds16(Xlo + abase + kt, &Al[buf][ldst]);
    gload_lds16(Xhi + bbase + kt, &Bh[buf][ldst]);
    gload_lds16(Xlo + bbase + kt, &Bl[buf][ldst]);
  };

  f32x4 acc = {};
  constexpr int NT = KDIM / 64;
  stage(0, 0);
  __syncthreads();
  for (int t = 0; t < NT; ++t) {
    if (t + 1 < NT) stage((t + 1) & 1, (t + 1) * 64);
    const int b = t & 1;
    const int ra = wm * 16 + r16, rb = wn * 16 + r16;
#pragma unroll
    for (int kk = 0; kk < 64; kk += 32) {
      int oa = ra * 64 + ((kk + kg * 8) ^ ((ra & 7) * 8));
      int ob = rb * 64 + ((kk + kg * 8) ^ ((rb & 7) * 8));
      bf16x8 ah = *(const bf16x8*)&Ah[b][oa];
      bf16x8 al = *(const bf16x8*)&Al[b][oa];
      bf16x8 bh = *(const bf16x8*)&Bh[b][ob];
      bf16x8 bl = *(const bf16x8*)&Bl[b][ob];
      acc = __builtin_amdgcn_mfma_f32_16x16x32_bf16(ah, bh, acc, 0, 0, 0);
      acc = __builtin_amdgcn_mfma_f32_16x16x32_bf16(ah, bl, acc, 0, 0, 0);
      acc = __builtin_amdgcn_mfma_f32_16x16x32_bf16(al, bh, acc, 0, 0, 0);
    }
    __syncthreads();
  }

  float fro = 0.0f;
#pragma unroll
  for (int r = 0; r < 4; ++r) {
    float c = acc[r] * s;
    int orow = i0 + wm * 16 + (lane >> 4) * 4 + r;
    int ocol = j0 + wn * 16 + r16;
    int idx = orow * 512 + ocol;
    bf16_t h = __float2bfloat16(c);
    Chi[idx] = h;
    Clo[idx] = __float2bfloat16(c - __bfloat162float(h));
    if constexpr (WF32) Cf[idx] = c;
    fro = fmaf(c, c, fro);
  }
  for (int off = 32; off; off >>= 1) fro += __shfl_down(fro, off, 64);
  if ((tid & 63) == 0) red[tid >> 6] = fro;
  __syncthreads();
  if (tid == 0) pout[bid] = red[0] + red[1] + red[2] + red[3];
}

// num_partial = sum(A0 .* B), den_partial = sum(diag(B))
__global__ __launch_bounds__(256) void k_dot(const float* __restrict__ A0,
                                             const float* __restrict__ B,
                                             float* __restrict__ numP,
                                             float* __restrict__ denP) {
  __shared__ float redn[4], redd[4];
  const int tid = threadIdx.x;
  const int idx4 = blockIdx.x * 256 + tid;
  const f32x4 a = ((const f32x4*)A0)[idx4];
  const f32x4 b = ((const f32x4*)B)[idx4];
  float nv = a[0]*b[0] + a[1]*b[1] + a[2]*b[2] + a[3]*b[3];
  float dv = 0.0f;
#pragma unroll
  for (int q = 0; q < 4; ++q) {
    int i = idx4 * 4 + q;
    if ((i >> 9) == (i & 511)) dv += b[q];
  }
  for (int off = 32; off; off >>= 1) {
    nv += __shfl_down(nv, off, 64);
    dv += __shfl_down(dv, off, 64);
  }
  if ((tid & 63) == 0) { redn[tid >> 6] = nv; redd[tid >> 6] = dv; }
  __syncthreads();
  if (tid == 0) {
    numP[blockIdx.x] = redn[0] + redn[1] + redn[2] + redn[3];
    denP[blockIdx.x] = redd[0] + redd[1] + redd[2] + redd[3];
  }
}

__global__ __launch_bounds__(256) void k_setup(const float* __restrict__ alpha,
                                               const float* __restrict__ beta,
                                               const float* __restrict__ numP,
                                               const float* __restrict__ denP,
                                               float* __restrict__ params) {
  __shared__ float redn[4], redd[4];
  __shared__ float Lsh;
  const int tid = threadIdx.x;
  float nv = numP[tid], dv = denP[tid];
  for (int off = 32; off; off >>= 1) {
    nv += __shfl_down(nv, off, 64);
    dv += __shfl_down(dv, off, 64);
  }
  if ((tid & 63) == 0) { redn[tid >> 6] = nv; redd[tid >> 6] = dv; }
  __syncthreads();
  if (tid == 0)
    Lsh = (redn[0] + redn[1] + redn[2] + redn[3]) /
          (redd[0] + redd[1] + redd[2] + redd[3]);
  __syncthreads();
  const int t = tid;
  if (t >= 10) return;
  float L = Lsh;
  float invL = 1.0f / L;
  float lam = 0.001f * invL;
  const float* a = alpha + t * 20;
  float mx = a[0];
  for (int k = 1; k < 20; ++k) mx = fmaxf(mx, a[k]);
  float e[20], ssum = 0.0f;
  for (int k = 0; k < 20; ++k) { e[k] = expf(a[k] - mx); ssum += e[k]; }
  float inv = 1.0f / ssum;
  float* P = params + t * 32;
  for (int k = 0; k < 20; ++k) P[k] = e[k] * inv;
  float b0 = beta[t * 2], b1 = beta[t * 2 + 1];
  float bm = fmaxf(b0, b1);
  float eb0 = expf(b0 - bm), eb1 = expf(b1 - bm);
  float bw0 = eb0 / (eb0 + eb1);
  P[20] = ((float)(t + 1) / (float)(t + 4)) * bw0;  // c_{i+1} * bw0_i
  P[21] = invL;
  P[22] = lam;
  P[23] = L;
}

// ================= 64x64-tile MFMA GEMMs, XOR-swizzled, double-buffered ====
// Stage(t+1) issued BEFORE compute(t): load latency overlaps the MFMA+ds_read
// phase; __syncthreads drains the remainder (minimal 2-phase, T3-min).

// ---------------- GEMM1: Wzx[b][n] = sum_h zaux[b][h]*W[n][h] - x[b][n] ----
__global__ __launch_bounds__(256) void k1_gemm(const bf16_t* __restrict__ A,
                                               const bf16_t* __restrict__ Bt,
                                               const bf16_t* __restrict__ xb,
                                               bf16_t* __restrict__ Wzx) {
  const int K = 1024;
  __shared__ __align__(16) unsigned short As[2][64 * 64], Bs[2][64 * 64];
  const int tid = threadIdx.x, lane = tid & 63, wave = tid >> 6;
  const int wm = wave >> 1, wn = wave & 1;
  int bid = blockIdx.x;
  int swz = (bid & 7) * 64 + (bid >> 3);          // XCD swizzle (512 % 8 == 0)
  const int m0 = (swz & 63) * 64, n0 = (swz >> 6) * 64;
  const int r16 = lane & 15, kg = lane >> 4;

  auto stage = [&](int buf, int kt) {
#pragma unroll
    for (int q = 0; q < 2; ++q) {
      int lin = (tid + q * 256) * 8;
      int row = lin >> 6;
      int col = ((((lin >> 3) & 7) ^ (row & 7)) << 3);
      gload_lds16(A + (long)(m0 + row) * K + kt + col, &As[buf][lin]);
      gload_lds16(Bt + (long)(n0 + row) * K + kt + col, &Bs[buf][lin]);
    }
  };

  f32x4 acc[2][2] = {};
  stage(0, 0);
  __syncthreads();
  for (int t = 0; t < K / 64; ++t) {
    if (t + 1 < K / 64) stage((t + 1) & 1, (t + 1) * 64);
    const int b = t & 1;
#pragma unroll
    for (int kk = 0; kk < 64; kk += 32) {
      bf16x8 a[2], bb[2];
#pragma unroll
      for (int f = 0; f < 2; ++f) {
        int ra = wm * 32 + f * 16 + r16;
        int rb = wn * 32 + f * 16 + r16;
        a[f]  = *(const bf16x8*)&As[b][ra * 64 + ((kk + kg * 8) ^ ((ra & 7) * 8))];
        bb[f] = *(const bf16x8*)&Bs[b][rb * 64 + ((kk + kg * 8) ^ ((rb & 7) * 8))];
      }
#pragma unroll
      for (int i = 0; i < 2; ++i)
#pragma unroll
        for (int j = 0; j < 2; ++j)
          acc[i][j] = __builtin_amdgcn_mfma_f32_16x16x32_bf16(a[i], bb[j], acc[i][j], 0, 0, 0);
    }
    __syncthreads();
  }
#pragma unroll
  for (int i = 0; i < 2; ++i)
#pragma unroll
    for (int j = 0; j < 2; ++j)
#pragma unroll
      for (int r = 0; r < 4; ++r) {
        int row = m0 + wm * 32 + i * 16 + (lane >> 4) * 4 + r;
        int col = n0 + wn * 32 + j * 16 + r16;
        int idx = row * 512 + col;
        Wzx[idx] = __float2bfloat16(acc[i][j][r] - __bfloat162float(xb[idx]));
      }
}

// ---------------- GEMM2 + epilogue --------------------------------------
// grad = Wzx·W^T(view); zg = zaux - grad/L; zop = mix(zg); z stored bf16 in zB;
// d_out (f32) written only on LAST iteration.
template <bool FIRST, bool LAST>
__global__ __launch_bounds__(256) void k2_gemm(const bf16_t* __restrict__ A,
                                               const bf16_t* __restrict__ Bt,
                                               bf16_t* zauxB,                 // [4096][1024]
                                               bf16_t* zB,                    // [4096][1024]
                                               float* zio,                    // d_out
                                               const float* __restrict__ prm) {
  const int K = 512, N = 1024;
  __shared__ __align__(16) unsigned short As[2][64 * 64], Bs[2][64 * 64];
  const int tid = threadIdx.x, lane = tid & 63, wave = tid >> 6;
  const int wm = wave >> 1, wn = wave & 1;
  int bid = blockIdx.x;
  int swz = (bid & 7) * 128 + (bid >> 3);         // XCD swizzle (1024 % 8 == 0)
  const int m0 = (swz & 63) * 64, n0 = (swz >> 6) * 64;
  const int r16 = lane & 15, kg = lane >> 4;

  auto stage = [&](int buf, int kt) {
#pragma unroll
    for (int q = 0; q < 2; ++q) {
      int lin = (tid + q * 256) * 8;
      int row = lin >> 6;
      int col = ((((lin >> 3) & 7) ^ (row & 7)) << 3);
      gload_lds16(A + (long)(m0 + row) * K + kt + col, &As[buf][lin]);
      gload_lds16(Bt + (long)(n0 + row) * K + kt + col, &Bs[buf][lin]);
    }
  };

  f32x4 acc[2][2] = {};
  stage(0, 0);
  __syncthreads();
  for (int t = 0; t < K / 64; ++t) {
    if (t + 1 < K / 64) stage((t + 1) & 1, (t + 1) * 64);
    const int b = t & 1;
#pragma unroll
    for (int kk = 0; kk < 64; kk += 32) {
      bf16x8 a[2], bb[2];
#pragma unroll
      for (int f = 0; f < 2; ++f) {
        int ra = wm * 32 + f * 16 + r16;
        int rb = wn * 32 + f * 16 + r16;
        a[f]  = *(const bf16x8*)&As[b][ra * 64 + ((kk + kg * 8) ^ ((ra & 7) * 8))];
        bb[f] = *(const bf16x8*)&Bs[b][rb * 64 + ((kk + kg * 8) ^ ((rb & 7) * 8))];
      }
#pragma unroll
      for (int i = 0; i < 2; ++i)
#pragma unroll
        for (int j = 0; j < 2; ++j)
          acc[i][j] = __builtin_amdgcn_mfma_f32_16x16x32_bf16(a[i], bb[j], acc[i][j], 0, 0, 0);
    }
    __syncthreads();
  }
  const float d_i = prm[20];
  const float invL = prm[21];
  const float lam = prm[22];
  float aw[20];
#pragma unroll
  for (int k = 0; k < 20; ++k) aw[k] = prm[k];
#pragma unroll
  for (int i = 0; i < 2; ++i)
#pragma unroll
    for (int j = 0; j < 2; ++j)
#pragma unroll
      for (int r = 0; r < 4; ++r) {
        int row = m0 + wm * 32 + i * 16 + (lane >> 4) * 4 + r;
        int col = n0 + wn * 32 + j * 16 + r16;
        long idx = (long)row * N + col;
        float grad = acc[i][j][r];
        float za = 0.0f, zold = 0.0f;
        if (!FIRST) {
          za = __bfloat162float(zauxB[idx]);
          zold = __bfloat162float(zB[idx]);
        }
        float zg = fmaf(-grad, invL, za);
        float zop = act_mix(zg, aw, lam);
        if (LAST) {
          zio[idx] = zop;
        } else {
          zB[idx] = __float2bfloat16(zop);
          float zx = fmaf(d_i, zop - zold, zop);
          zauxB[idx] = __float2bfloat16(zx);
        }
      }
}

// ---------------- orchestration ----------------
extern "C" void kernel_launch(void* const* d_in, const int* in_sizes, int n_in,
                              void* d_out, int out_size, void* d_ws, size_t ws_size,
                              hipStream_t stream) {
  const float* x     = (const float*)d_in[0];
  const float* W     = (const float*)d_in[1];
  const float* alpha = (const float*)d_in[2];
  const float* beta  = (const float*)d_in[3];
  float* zout = (float*)d_out;

  char* ws = (char*)d_ws;
  const size_t MB = 1u << 20;
  float* pb[13];
  for (int k = 0; k < 13; ++k) pb[k] = (float*)(ws + (size_t)k * 1024);
  float* numP   = (float*)(ws + 13 * 1024);
  float* denP   = (float*)(ws + 14 * 1024);
  float* params = (float*)(ws + 15 * 1024);
  const size_t HDR = 32768;
  // ws_size evidenced at 256MB (round-3 fill WRITE_SIZE); we use ~31MB.
  float*  A0f  = (float*)(ws + HDR);                 // 1 MB
  float*  Bf   = (float*)(ws + HDR + 1 * MB);        // 1 MB
  bf16_t* H0   = (bf16_t*)(ws + HDR + 2 * MB);       // 0.5 MB
  bf16_t* L0   = (bf16_t*)(ws + HDR + 2 * MB + 512 * 1024);
  bf16_t* H1   = (bf16_t*)(ws + HDR + 3 * MB);
  bf16_t* L1   = (bf16_t*)(ws + HDR + 3 * MB + 512 * 1024);
  bf16_t* Whi  = (bf16_t*)(ws + HDR + 4 * MB);       // 1 MB
  bf16_t* Wlo  = (bf16_t*)(ws + HDR + 5 * MB);       // 1 MB
  bf16_t* Wt   = (bf16_t*)(ws + HDR + 6 * MB);       // 1 MB
  bf16_t* xb   = (bf16_t*)(ws + HDR + 7 * MB);       // 4 MB
  bf16_t* Wzx  = (bf16_t*)(ws + HDR + 11 * MB);      // 4 MB
  bf16_t* zauxB= (bf16_t*)(ws + HDR + 15 * MB);      // 8 MB
  bf16_t* zB   = (bf16_t*)(ws + HDR + 23 * MB);      // 8 MB

  k_cast<<<2048, 256, 0, stream>>>(W, Whi, Wlo, Wt);
  k_prep<<<8192, 256, 0, stream>>>(x, xb, Wzx);

  // L: A0 = W*W^T (hi/lo MFMA), 12 normalized squarings, Rayleigh via traces
  k_sqm<1024, true, true><<<dim3(16, 16), 256, 0, stream>>>(
      Whi, Wlo, H0, L0, A0f, nullptr, pb[0]);
  bf16_t* Hs[2] = {H0, H1};
  bf16_t* Ls[2] = {L0, L1};
  int pp = 0;
  for (int k = 0; k < 12; ++k) {
    if (k == 11)
      k_sqm<512, false, true><<<dim3(16, 16), 256, 0, stream>>>(
          Hs[pp], Ls[pp], Hs[pp ^ 1], Ls[pp ^ 1], Bf, pb[k], pb[k + 1]);
    else
      k_sqm<512, false, false><<<dim3(16, 16), 256, 0, stream>>>(
          Hs[pp], Ls[pp], Hs[pp ^ 1], Ls[pp ^ 1], nullptr, pb[k], pb[k + 1]);
    pp ^= 1;
  }
  k_dot<<<256, 256, 0, stream>>>(A0f, Bf, numP, denP);
  k_setup<<<1, 256, 0, stream>>>(alpha, beta, numP, denP, params);

  // iter 0: zaux=0 -> Wzx = -x (from k_prep)
  k2_gemm<true, false><<<1024, 256, 0, stream>>>(Wzx, Wt, zauxB, zB, zout, params);

  for (int i = 1; i < 10; ++i) {
    k1_gemm<<<512, 256, 0, stream>>>(zauxB, Whi, xb, Wzx);
    const float* prm = params + i * 32;
    if (i < 9)
      k2_gemm<false, false><<<1024, 256, 0, stream>>>(Wzx, Wt, zauxB, zB, zout, prm);
    else
      k2_gemm<false, true><<<1024, 256, 0, stream>>>(Wzx, Wt, zauxB, zB, zout, prm);
  }
}

// Round 5
// 525.999 us; speedup vs baseline: 2.4321x; 1.0330x over previous
//
#include <hip/hip_runtime.h>
#include <hip/hip_bf16.h>

#define DI __device__ __forceinline__

typedef float f32x4 __attribute__((ext_vector_type(4)));
typedef __bf16 bf16x8 __attribute__((ext_vector_type(8)));
using bf16_t = __hip_bfloat16;
using ushort_t = unsigned short;

// ---------------- async global->LDS (16B per lane) ----------------
DI void gload_lds16(const void* g, void* l) {
  __builtin_amdgcn_global_load_lds(
      (const __attribute__((address_space(1))) void*)g,
      (__attribute__((address_space(3))) void*)l, 16, 0, 0);
}

DI float rcpf(float x) { return __builtin_amdgcn_rcpf(x); }

// ---------------- 20-way weighted activation mixture ----------------
DI float act_mix(float x, const float* aw, float lam) {
  const float ax  = fabsf(x);
  const float en  = __expf(-ax);        // e^{-|x|} in (0,1]
  const float en2 = en * en;            // e^{-2|x|}
  const float i1  = rcpf(1.0f + en);
  const float sig = (x >= 0.0f) ? i1 : en * i1;            // sigmoid
  const float th  = copysignf((1.0f - en2) * rcpf(1.0f + en2), x); // tanh
  const float l1p = __logf(1.0f + en);
  const float sp  = fmaxf(x, 0.0f) + l1p;                  // softplus
  const float lsg = fminf(x, 0.0f) - l1p;                  // logsigmoid
  const float q   = ((x >= 0.0f) ? en2 : 1.0f) * (i1 * i1);// e^{-2*softplus}
  const float mish = x * (1.0f - q) * rcpf(1.0f + q);
  // gelu exact via A&S 7.1.26 erf approx (|err|<=1.5e-7)
  const float u  = 0.7071067811865476f * x;
  const float au = fabsf(u);
  const float t  = rcpf(1.0f + 0.3275911f * au);
  float poly = fmaf(t, 1.061405429f, -1.453152027f);
  poly = fmaf(t, poly, 1.421413741f);
  poly = fmaf(t, poly, -0.284496736f);
  poly = fmaf(t, poly, 0.254829592f);
  poly *= t;
  const float erfa = 1.0f - poly * __expf(-u * u);
  const float gelu = 0.5f * x * (1.0f + copysignf(erfa, x));
  const float em1  = en - 1.0f;                            // e^x-1 for x<=0
  const float elu  = (x > 0.0f) ? x : em1;
  const float selu = (x > 0.0f) ? 1.0507009873554805f * x : 1.7580993408473766f * em1;
  const float relu = fmaxf(x, 0.0f);
  const float t6   = fminf(fmaxf(x + 3.0f, 0.0f), 6.0f) * 0.16666666666666666f;
  const float ssh  = (x > lam) ? (x - lam) : ((x < -lam) ? (x + lam) : 0.0f);
  const float hsh  = (ax > lam) ? x : 0.0f;
  const float htan = fminf(fmaxf(x, -1.0f), 1.0f);
  const float lky  = (x >= 0.0f) ? x : 0.01f * x;
  const float ssn  = x * rcpf(1.0f + ax);
  float r = aw[0] * ssh;
  r = fmaf(aw[1],  relu,   r);
  r = fmaf(aw[2],  x,      r);
  r = fmaf(aw[3],  gelu,   r);
  r = fmaf(aw[4],  elu,    r);
  r = fmaf(aw[5],  hsh,    r);
  r = fmaf(aw[6],  htan,   r);
  r = fmaf(aw[7],  x * t6, r);
  r = fmaf(aw[8],  selu,   r);
  r = fmaf(aw[9],  elu,    r);   // celu(alpha=1) == elu
  r = fmaf(aw[10], lky,    r);
  r = fmaf(aw[11], lsg,    r);
  r = fmaf(aw[12], x - th, r);
  r = fmaf(aw[13], ssn,    r);
  r = fmaf(aw[14], sp,     r);
  r = fmaf(aw[15], th,     r);
  r = fmaf(aw[16], sig,    r);
  r = fmaf(aw[17], t6,     r);
  r = fmaf(aw[18], x * sig, r);
  r = fmaf(aw[19], mish,   r);
  return r;
}

// ---------------- fused prep: hi/lo splits of W (and W^T) and x ----------------
__global__ void k_prep(const float* __restrict__ W, const float* __restrict__ x,
                       bf16_t* __restrict__ Whi, bf16_t* __restrict__ Wlo,
                       bf16_t* __restrict__ Wth, bf16_t* __restrict__ Wtl,
                       bf16_t* __restrict__ xh, bf16_t* __restrict__ xl) {
  int i = blockIdx.x * 256 + threadIdx.x;
  if (i < 512 * 1024) {
    float w = W[i];
    bf16_t h = __float2bfloat16(w);
    bf16_t l = __float2bfloat16(w - __bfloat162float(h));
    Whi[i] = h; Wlo[i] = l;
    int n = i >> 10, hc = i & 1023;
    Wth[hc * 512 + n] = h; Wtl[hc * 512 + n] = l;
  }
  int j = i - 512 * 1024;
  if (j >= 0 && j < 4096 * 512) {
    float v = x[j];
    bf16_t h = __float2bfloat16(v);
    xh[j] = h;
    xl[j] = __float2bfloat16(v - __bfloat162float(h));
  }
}

// ---------------- L pipeline: MFMA hi/lo squaring (round-4, unchanged) -------
// 9 squarings suffice: Rayleigh weight (lam2/lam1)^512 with edge gap ~N^{-2/3}
// ~0.016 gives e^{-8.3}~2.6e-4 mode weight -> relative L error <1e-4.
template <int KDIM, bool FIRST, bool WF32>
__global__ __launch_bounds__(256) void k_sqm(
    const bf16_t* __restrict__ Xhi, const bf16_t* __restrict__ Xlo,
    bf16_t* __restrict__ Chi, bf16_t* __restrict__ Clo,
    float* __restrict__ Cf,
    const float* __restrict__ pin, float* __restrict__ pout) {
  __shared__ __align__(16) ushort_t Ah[2][32 * 64], Al[2][32 * 64],
                                    Bh[2][32 * 64], Bl[2][32 * 64];
  __shared__ float red[4];
  const int tid = threadIdx.x, lane = tid & 63, wave = tid >> 6;
  const int wm = wave >> 1, wn = wave & 1;
  const int i0 = blockIdx.x * 32, j0 = blockIdx.y * 32;
  const int bid = blockIdx.y * gridDim.x + blockIdx.x;
  const int r16 = lane & 15, kg = lane >> 4;

  float s = 1.0f;
  if constexpr (!FIRST) {
    float v = pin[tid];
    for (int off = 32; off; off >>= 1) v += __shfl_down(v, off, 64);
    if ((tid & 63) == 0) red[tid >> 6] = v;
    __syncthreads();
    s = 1.0f / (red[0] + red[1] + red[2] + red[3]);
    __syncthreads();
  }

  const int row = tid >> 3;
  const int srcc = (((tid & 7) ^ (row & 7)) << 3);
  const long abase = (long)(i0 + row) * KDIM + srcc;
  const long bbase = (long)(j0 + row) * KDIM + srcc;
  const int ldst = tid * 8;

  auto stage = [&](int buf, int kt) {
    gload_lds16(Xhi + abase + kt, &Ah[buf][ldst]);
    gload_lds16(Xlo + abase + kt, &Al[buf][ldst]);
    gload_lds16(Xhi + bbase + kt, &Bh[buf][ldst]);
    gload_lds16(Xlo + bbase + kt, &Bl[buf][ldst]);
  };

  f32x4 acc = {};
  constexpr int NT = KDIM / 64;
  stage(0, 0);
  __syncthreads();
  for (int t = 0; t < NT; ++t) {
    if (t + 1 < NT) stage((t + 1) & 1, (t + 1) * 64);
    const int b = t & 1;
    const int ra = wm * 16 + r16, rb = wn * 16 + r16;
#pragma unroll
    for (int kk = 0; kk < 64; kk += 32) {
      int oa = ra * 64 + ((kk + kg * 8) ^ ((ra & 7) * 8));
      int ob = rb * 64 + ((kk + kg * 8) ^ ((rb & 7) * 8));
      bf16x8 ah = *(const bf16x8*)&Ah[b][oa];
      bf16x8 al = *(const bf16x8*)&Al[b][oa];
      bf16x8 bh = *(const bf16x8*)&Bh[b][ob];
      bf16x8 bl = *(const bf16x8*)&Bl[b][ob];
      acc = __builtin_amdgcn_mfma_f32_16x16x32_bf16(ah, bh, acc, 0, 0, 0);
      acc = __builtin_amdgcn_mfma_f32_16x16x32_bf16(ah, bl, acc, 0, 0, 0);
      acc = __builtin_amdgcn_mfma_f32_16x16x32_bf16(al, bh, acc, 0, 0, 0);
    }
    __syncthreads();
  }

  float fro = 0.0f;
#pragma unroll
  for (int r = 0; r < 4; ++r) {
    float c = acc[r] * s;
    int orow = i0 + wm * 16 + (lane >> 4) * 4 + r;
    int ocol = j0 + wn * 16 + r16;
    int idx = orow * 512 + ocol;
    bf16_t h = __float2bfloat16(c);
    Chi[idx] = h;
    Clo[idx] = __float2bfloat16(c - __bfloat162float(h));
    if constexpr (WF32) Cf[idx] = c;
    fro = fmaf(c, c, fro);
  }
  for (int off = 32; off; off >>= 1) fro += __shfl_down(fro, off, 64);
  if ((tid & 63) == 0) red[tid >> 6] = fro;
  __syncthreads();
  if (tid == 0) pout[bid] = red[0] + red[1] + red[2] + red[3];
}

// ---------------- G = W^T W (1024x1024) from hi/lo W^T, output single bf16 ---
// G computed f32-accurate (3-term hi/lo MFMA), rounded ONCE -> this replaces
// the per-iter {W-round x2, Wzx-round} of the two-GEMM chain.
__global__ __launch_bounds__(256) void k_G(const bf16_t* __restrict__ Xhi,
                                           const bf16_t* __restrict__ Xlo,
                                           bf16_t* __restrict__ G) {
  __shared__ __align__(16) ushort_t Ah[2][32 * 64], Al[2][32 * 64],
                                    Bh[2][32 * 64], Bl[2][32 * 64];
  const int tid = threadIdx.x, lane = tid & 63, wave = tid >> 6;
  const int wm = wave >> 1, wn = wave & 1;
  const int i0 = blockIdx.x * 32, j0 = blockIdx.y * 32;
  const int r16 = lane & 15, kg = lane >> 4;
  const int row = tid >> 3;
  const int srcc = (((tid & 7) ^ (row & 7)) << 3);
  const long abase = (long)(i0 + row) * 512 + srcc;
  const long bbase = (long)(j0 + row) * 512 + srcc;
  const int ldst = tid * 8;

  auto stage = [&](int buf, int kt) {
    gload_lds16(Xhi + abase + kt, &Ah[buf][ldst]);
    gload_lds16(Xlo + abase + kt, &Al[buf][ldst]);
    gload_lds16(Xhi + bbase + kt, &Bh[buf][ldst]);
    gload_lds16(Xlo + bbase + kt, &Bl[buf][ldst]);
  };

  f32x4 acc = {};
  stage(0, 0);
  __syncthreads();
  for (int t = 0; t < 8; ++t) {
    if (t + 1 < 8) stage((t + 1) & 1, (t + 1) * 64);
    const int b = t & 1;
    const int ra = wm * 16 + r16, rb = wn * 16 + r16;
#pragma unroll
    for (int kk = 0; kk < 64; kk += 32) {
      int oa = ra * 64 + ((kk + kg * 8) ^ ((ra & 7) * 8));
      int ob = rb * 64 + ((kk + kg * 8) ^ ((rb & 7) * 8));
      bf16x8 ah = *(const bf16x8*)&Ah[b][oa];
      bf16x8 al = *(const bf16x8*)&Al[b][oa];
      bf16x8 bh = *(const bf16x8*)&Bh[b][ob];
      bf16x8 bl = *(const bf16x8*)&Bl[b][ob];
      acc = __builtin_amdgcn_mfma_f32_16x16x32_bf16(ah, bh, acc, 0, 0, 0);
      acc = __builtin_amdgcn_mfma_f32_16x16x32_bf16(ah, bl, acc, 0, 0, 0);
      acc = __builtin_amdgcn_mfma_f32_16x16x32_bf16(al, bh, acc, 0, 0, 0);
    }
    __syncthreads();
  }
#pragma unroll
  for (int r = 0; r < 4; ++r) {
    int orow = i0 + wm * 16 + (lane >> 4) * 4 + r;
    int ocol = j0 + wn * 16 + r16;
    G[orow * 1024 + ocol] = __float2bfloat16(acc[r]);
  }
}

// ---------------- xW = x·W (4096x1024, f32, exact via 3-term hi/lo) ----------
__global__ __launch_bounds__(256) void k_xw(const bf16_t* __restrict__ xh_,
                                            const bf16_t* __restrict__ xl_,
                                            const bf16_t* __restrict__ Bh_,
                                            const bf16_t* __restrict__ Bl_,
                                            float* __restrict__ out) {
  __shared__ __align__(16) ushort_t Axh[2][64 * 64], Axl[2][64 * 64],
                                    Bwh[2][64 * 64], Bwl[2][64 * 64];
  const int tid = threadIdx.x, lane = tid & 63, wave = tid >> 6;
  const int wm = wave >> 1, wn = wave & 1;
  const int m0 = blockIdx.x * 64, n0 = blockIdx.y * 64;
  const int r16 = lane & 15, kg = lane >> 4;

  auto stage = [&](int buf, int kt) {
#pragma unroll
    for (int q = 0; q < 2; ++q) {
      int lin = (tid + q * 256) * 8;
      int row = lin >> 6;
      int col = ((((lin >> 3) & 7) ^ (row & 7)) << 3);
      gload_lds16(xh_ + (long)(m0 + row) * 512 + kt + col, &Axh[buf][lin]);
      gload_lds16(xl_ + (long)(m0 + row) * 512 + kt + col, &Axl[buf][lin]);
      gload_lds16(Bh_ + (long)(n0 + row) * 512 + kt + col, &Bwh[buf][lin]);
      gload_lds16(Bl_ + (long)(n0 + row) * 512 + kt + col, &Bwl[buf][lin]);
    }
  };

  f32x4 acc[2][2] = {};
  stage(0, 0);
  __syncthreads();
  for (int t = 0; t < 8; ++t) {
    if (t + 1 < 8) stage((t + 1) & 1, (t + 1) * 64);
    const int b = t & 1;
#pragma unroll
    for (int kk = 0; kk < 64; kk += 32) {
      bf16x8 ah[2], al[2], bh[2], bl[2];
#pragma unroll
      for (int f = 0; f < 2; ++f) {
        int ra = wm * 32 + f * 16 + r16;
        int rb = wn * 32 + f * 16 + r16;
        int oa = ra * 64 + ((kk + kg * 8) ^ ((ra & 7) * 8));
        int ob = rb * 64 + ((kk + kg * 8) ^ ((rb & 7) * 8));
        ah[f] = *(const bf16x8*)&Axh[b][oa];
        al[f] = *(const bf16x8*)&Axl[b][oa];
        bh[f] = *(const bf16x8*)&Bwh[b][ob];
        bl[f] = *(const bf16x8*)&Bwl[b][ob];
      }
#pragma unroll
      for (int i = 0; i < 2; ++i)
#pragma unroll
        for (int j = 0; j < 2; ++j) {
          acc[i][j] = __builtin_amdgcn_mfma_f32_16x16x32_bf16(ah[i], bh[j], acc[i][j], 0, 0, 0);
          acc[i][j] = __builtin_amdgcn_mfma_f32_16x16x32_bf16(ah[i], bl[j], acc[i][j], 0, 0, 0);
          acc[i][j] = __builtin_amdgcn_mfma_f32_16x16x32_bf16(al[i], bh[j], acc[i][j], 0, 0, 0);
        }
    }
    __syncthreads();
  }
#pragma unroll
  for (int i = 0; i < 2; ++i)
#pragma unroll
    for (int j = 0; j < 2; ++j)
#pragma unroll
      for (int r = 0; r < 4; ++r) {
        int row = m0 + wm * 32 + i * 16 + (lane >> 4) * 4 + r;
        int col = n0 + wn * 32 + j * 16 + r16;
        out[(long)row * 1024 + col] = acc[i][j][r];
      }
}

// ---------------- Rayleigh num/den partials ----------------
__global__ __launch_bounds__(256) void k_dot(const float* __restrict__ A0,
                                             const float* __restrict__ B,
                                             float* __restrict__ numP,
                                             float* __restrict__ denP) {
  __shared__ float redn[4], redd[4];
  const int tid = threadIdx.x;
  const int idx4 = blockIdx.x * 256 + tid;
  const f32x4 a = ((const f32x4*)A0)[idx4];
  const f32x4 b = ((const f32x4*)B)[idx4];
  float nv = a[0]*b[0] + a[1]*b[1] + a[2]*b[2] + a[3]*b[3];
  float dv = 0.0f;
#pragma unroll
  for (int q = 0; q < 4; ++q) {
    int i = idx4 * 4 + q;
    if ((i >> 9) == (i & 511)) dv += b[q];
  }
  for (int off = 32; off; off >>= 1) {
    nv += __shfl_down(nv, off, 64);
    dv += __shfl_down(dv, off, 64);
  }
  if ((tid & 63) == 0) { redn[tid >> 6] = nv; redd[tid >> 6] = dv; }
  __syncthreads();
  if (tid == 0) {
    numP[blockIdx.x] = redn[0] + redn[1] + redn[2] + redn[3];
    denP[blockIdx.x] = redd[0] + redd[1] + redd[2] + redd[3];
  }
}

__global__ __launch_bounds__(256) void k_setup(const float* __restrict__ alpha,
                                               const float* __restrict__ beta,
                                               const float* __restrict__ numP,
                                               const float* __restrict__ denP,
                                               float* __restrict__ params) {
  __shared__ float redn[4], redd[4];
  __shared__ float Lsh;
  const int tid = threadIdx.x;
  float nv = numP[tid], dv = denP[tid];
  for (int off = 32; off; off >>= 1) {
    nv += __shfl_down(nv, off, 64);
    dv += __shfl_down(dv, off, 64);
  }
  if ((tid & 63) == 0) { redn[tid >> 6] = nv; redd[tid >> 6] = dv; }
  __syncthreads();
  if (tid == 0)
    Lsh = (redn[0] + redn[1] + redn[2] + redn[3]) /
          (redd[0] + redd[1] + redd[2] + redd[3]);
  __syncthreads();
  const int t = tid;
  if (t >= 10) return;
  float L = Lsh;
  float invL = 1.0f / L;
  float lam = 0.001f * invL;
  const float* a = alpha + t * 20;
  float mx = a[0];
  for (int k = 1; k < 20; ++k) mx = fmaxf(mx, a[k]);
  float e[20], ssum = 0.0f;
  for (int k = 0; k < 20; ++k) { e[k] = expf(a[k] - mx); ssum += e[k]; }
  float inv = 1.0f / ssum;
  float* P = params + t * 32;
  for (int k = 0; k < 20; ++k) P[k] = e[k] * inv;
  float b0 = beta[t * 2], b1 = beta[t * 2 + 1];
  float bm = fmaxf(b0, b1);
  float eb0 = expf(b0 - bm), eb1 = expf(b1 - bm);
  float bw0 = eb0 / (eb0 + eb1);
  P[20] = ((float)(t + 1) / (float)(t + 4)) * bw0;  // c_{i+1} * bw0_i
  P[21] = invL;
  P[22] = lam;
  P[23] = L;
}

// ---------------- iteration 0: zaux=0 -> zg = xW*invL (pure elementwise) -----
__global__ __launch_bounds__(256) void k_it0(const float* __restrict__ xW,
                                             bf16_t* __restrict__ zauxB,
                                             bf16_t* __restrict__ zB,
                                             const float* __restrict__ prm) {
  const int i = blockIdx.x * 256 + threadIdx.x;   // f32x4 index, 4096*1024/4
  const float d = prm[20], invL = prm[21], lam = prm[22];
  float aw[20];
#pragma unroll
  for (int k = 0; k < 20; ++k) aw[k] = prm[k];
  f32x4 v = ((const f32x4*)xW)[i];
#pragma unroll
  for (int r = 0; r < 4; ++r) {
    float zop = act_mix(v[r] * invL, aw, lam);
    zB[i * 4 + r] = __float2bfloat16(zop);
    zauxB[i * 4 + r] = __float2bfloat16(zop * (1.0f + d));  // zold = 0
  }
}

// ---------------- main iteration: acc = zaux·G; epilogue -------------------
// zg = zaux + (xW - acc)*invL; zop = mix(zg); zB=zop; zauxB=zop+d*(zop-zold).
// 128x64 tile, 4 waves (2m x 2n), wave=64x32 (acc[4][2]), K=1024, dbuf swizzled.
template <bool LAST>
__global__ __launch_bounds__(256) void k_iter(const bf16_t* __restrict__ A,  // zauxB
                                              const bf16_t* __restrict__ G,
                                              const float* __restrict__ xW,
                                              bf16_t* zauxB, bf16_t* zB,
                                              float* zio,
                                              const float* __restrict__ prm) {
  __shared__ __align__(16) ushort_t As[2][128 * 64], Bs[2][64 * 64];
  const int tid = threadIdx.x, lane = tid & 63, wave = tid >> 6;
  const int wm = wave >> 1, wn = wave & 1;
  const int bid = blockIdx.x;
  const int swz = (bid & 7) * 64 + (bid >> 3);    // XCD swizzle (512 % 8 == 0)
  const int m0 = (swz >> 4) * 128, n0 = (swz & 15) * 64;
  const int r16 = lane & 15, kg = lane >> 4;

  auto stage = [&](int buf, int kt) {
#pragma unroll
    for (int q = 0; q < 4; ++q) {
      int lin = (tid + q * 256) * 8;
      int row = lin >> 6;
      int col = ((((lin >> 3) & 7) ^ (row & 7)) << 3);
      gload_lds16(A + (long)(m0 + row) * 1024 + kt + col, &As[buf][lin]);
      if (q < 2)
        gload_lds16(G + (long)(n0 + row) * 1024 + kt + col, &Bs[buf][lin]);
    }
  };

  f32x4 acc[4][2] = {};
  stage(0, 0);
  __syncthreads();
  for (int t = 0; t < 16; ++t) {
    if (t + 1 < 16) stage((t + 1) & 1, (t + 1) * 64);
    const int b = t & 1;
#pragma unroll
    for (int kk = 0; kk < 64; kk += 32) {
      bf16x8 a[4], bb[2];
#pragma unroll
      for (int f = 0; f < 4; ++f) {
        int ra = wm * 64 + f * 16 + r16;
        a[f] = *(const bf16x8*)&As[b][ra * 64 + ((kk + kg * 8) ^ ((ra & 7) * 8))];
      }
#pragma unroll
      for (int f = 0; f < 2; ++f) {
        int rb = wn * 32 + f * 16 + r16;
        bb[f] = *(const bf16x8*)&Bs[b][rb * 64 + ((kk + kg * 8) ^ ((rb & 7) * 8))];
      }
#pragma unroll
      for (int i = 0; i < 4; ++i)
#pragma unroll
        for (int j = 0; j < 2; ++j)
          acc[i][j] = __builtin_amdgcn_mfma_f32_16x16x32_bf16(a[i], bb[j], acc[i][j], 0, 0, 0);
    }
    __syncthreads();
  }

  const float d_i = prm[20];
  const float invL = prm[21];
  const float lam = prm[22];
  float aw[20];
#pragma unroll
  for (int k = 0; k < 20; ++k) aw[k] = prm[k];
#pragma unroll
  for (int i = 0; i < 4; ++i)
#pragma unroll
    for (int j = 0; j < 2; ++j)
#pragma unroll
      for (int r = 0; r < 4; ++r) {
        int row = m0 + wm * 64 + i * 16 + (lane >> 4) * 4 + r;
        int col = n0 + wn * 32 + j * 16 + r16;
        long idx = (long)row * 1024 + col;
        float za = __bfloat162float(A[idx]);        // zaux_i (bf16, same as operand)
        float zg = fmaf(xW[idx] - acc[i][j][r], invL, za);
        float zop = act_mix(zg, aw, lam);
        if (LAST) {
          zio[idx] = zop;
        } else {
          float zold = __bfloat162float(zB[idx]);
          zB[idx] = __float2bfloat16(zop);
          zauxB[idx] = __float2bfloat16(fmaf(d_i, zop - zold, zop));
        }
      }
}

// ---------------- orchestration ----------------
extern "C" void kernel_launch(void* const* d_in, const int* in_sizes, int n_in,
                              void* d_out, int out_size, void* d_ws, size_t ws_size,
                              hipStream_t stream) {
  const float* x     = (const float*)d_in[0];
  const float* W     = (const float*)d_in[1];
  const float* alpha = (const float*)d_in[2];
  const float* beta  = (const float*)d_in[3];
  float* zout = (float*)d_out;

  char* ws = (char*)d_ws;
  const size_t MB = 1u << 20;
  float* pb[11];
  for (int k = 0; k < 11; ++k) pb[k] = (float*)(ws + (size_t)k * 1024);
  float* numP   = (float*)(ws + 12 * 1024);
  float* denP   = (float*)(ws + 13 * 1024);
  float* params = (float*)(ws + 14 * 1024);
  const size_t HDR = 32768;
  float*  A0f  = (float*)(ws + HDR);                 // 1 MB
  float*  Bf   = (float*)(ws + HDR + 1 * MB);        // 1 MB
  bf16_t* H0   = (bf16_t*)(ws + HDR + 2 * MB);       // 0.5 MB
  bf16_t* L0   = (bf16_t*)(ws + HDR + 2 * MB + 512 * 1024);
  bf16_t* H1   = (bf16_t*)(ws + HDR + 3 * MB);
  bf16_t* L1   = (bf16_t*)(ws + HDR + 3 * MB + 512 * 1024);
  bf16_t* Whi  = (bf16_t*)(ws + HDR + 4 * MB);       // 1 MB
  bf16_t* Wlo  = (bf16_t*)(ws + HDR + 5 * MB);       // 1 MB
  bf16_t* Wth  = (bf16_t*)(ws + HDR + 6 * MB);       // 1 MB
  bf16_t* Wtl  = (bf16_t*)(ws + HDR + 7 * MB);       // 1 MB
  bf16_t* Gm   = (bf16_t*)(ws + HDR + 8 * MB);       // 2 MB
  bf16_t* xh   = (bf16_t*)(ws + HDR + 10 * MB);      // 4 MB
  bf16_t* xl   = (bf16_t*)(ws + HDR + 14 * MB);      // 4 MB
  float*  xW   = (float*)(ws + HDR + 18 * MB);       // 16 MB
  bf16_t* zauxB= (bf16_t*)(ws + HDR + 34 * MB);      // 8 MB
  bf16_t* zB   = (bf16_t*)(ws + HDR + 42 * MB);      // 8 MB  (~50 MB of 256 MB)

  k_prep<<<10240, 256, 0, stream>>>(W, x, Whi, Wlo, Wth, Wtl, xh, xl);

  // G and xW (L-independent)
  k_G<<<dim3(32, 32), 256, 0, stream>>>(Wth, Wtl, Gm);
  k_xw<<<dim3(64, 16), 256, 0, stream>>>(xh, xl, Wth, Wtl, xW);

  // L: A0 = W*W^T (hi/lo MFMA), 9 normalized squarings, Rayleigh via traces
  k_sqm<1024, true, true><<<dim3(16, 16), 256, 0, stream>>>(
      Whi, Wlo, H0, L0, A0f, nullptr, pb[0]);
  bf16_t* Hs[2] = {H0, H1};
  bf16_t* Ls[2] = {L0, L1};
  int pp = 0;
  for (int k = 0; k < 9; ++k) {
    if (k == 8)
      k_sqm<512, false, true><<<dim3(16, 16), 256, 0, stream>>>(
          Hs[pp], Ls[pp], Hs[pp ^ 1], Ls[pp ^ 1], Bf, pb[k], pb[k + 1]);
    else
      k_sqm<512, false, false><<<dim3(16, 16), 256, 0, stream>>>(
          Hs[pp], Ls[pp], Hs[pp ^ 1], Ls[pp ^ 1], nullptr, pb[k], pb[k + 1]);
    pp ^= 1;
  }
  k_dot<<<256, 256, 0, stream>>>(A0f, Bf, numP, denP);
  k_setup<<<1, 256, 0, stream>>>(alpha, beta, numP, denP, params);

  // iter 0 (zaux = 0): pure elementwise
  k_it0<<<4096, 256, 0, stream>>>(xW, zauxB, zB, params);

  // iters 1..9: single fused GEMM+epilogue each
  for (int i = 1; i < 9; ++i)
    k_iter<false><<<512, 256, 0, stream>>>(zauxB, Gm, xW, zauxB, zB, zout,
                                           params + i * 32);
  k_iter<true><<<512, 256, 0, stream>>>(zauxB, Gm, xW, zauxB, zB, zout,
                                        params + 9 * 32);
}

// Round 6
// 470.875 us; speedup vs baseline: 2.7168x; 1.1171x over previous
//
#include <hip/hip_runtime.h>
#include <hip/hip_bf16.h>

#define DI __device__ __forceinline__

typedef float f32x4 __attribute__((ext_vector_type(4)));
typedef __bf16 bf16x8 __attribute__((ext_vector_type(8)));
using bf16_t = __hip_bfloat16;
using ushort_t = unsigned short;

// ---------------- async global->LDS (16B per lane) ----------------
DI void gload_lds16(const void* g, void* l) {
  __builtin_amdgcn_global_load_lds(
      (const __attribute__((address_space(1))) void*)g,
      (__attribute__((address_space(3))) void*)l, 16, 0, 0);
}

DI float rcpf(float x) { return __builtin_amdgcn_rcpf(x); }

// ---------------- 20-way weighted activation mixture ----------------
DI float act_mix(float x, const float* aw, float lam) {
  const float ax  = fabsf(x);
  const float en  = __expf(-ax);        // e^{-|x|} in (0,1]
  const float en2 = en * en;            // e^{-2|x|}
  const float i1  = rcpf(1.0f + en);
  const float sig = (x >= 0.0f) ? i1 : en * i1;            // sigmoid
  const float th  = copysignf((1.0f - en2) * rcpf(1.0f + en2), x); // tanh
  const float l1p = __logf(1.0f + en);
  const float sp  = fmaxf(x, 0.0f) + l1p;                  // softplus
  const float lsg = fminf(x, 0.0f) - l1p;                  // logsigmoid
  const float q   = ((x >= 0.0f) ? en2 : 1.0f) * (i1 * i1);// e^{-2*softplus}
  const float mish = x * (1.0f - q) * rcpf(1.0f + q);
  // gelu exact via A&S 7.1.26 erf approx (|err|<=1.5e-7)
  const float u  = 0.7071067811865476f * x;
  const float au = fabsf(u);
  const float t  = rcpf(1.0f + 0.3275911f * au);
  float poly = fmaf(t, 1.061405429f, -1.453152027f);
  poly = fmaf(t, poly, 1.421413741f);
  poly = fmaf(t, poly, -0.284496736f);
  poly = fmaf(t, poly, 0.254829592f);
  poly *= t;
  const float erfa = 1.0f - poly * __expf(-u * u);
  const float gelu = 0.5f * x * (1.0f + copysignf(erfa, x));
  const float em1  = en - 1.0f;                            // e^x-1 for x<=0
  const float elu  = (x > 0.0f) ? x : em1;
  const float selu = (x > 0.0f) ? 1.0507009873554805f * x : 1.7580993408473766f * em1;
  const float relu = fmaxf(x, 0.0f);
  const float t6   = fminf(fmaxf(x + 3.0f, 0.0f), 6.0f) * 0.16666666666666666f;
  const float ssh  = (x > lam) ? (x - lam) : ((x < -lam) ? (x + lam) : 0.0f);
  const float hsh  = (ax > lam) ? x : 0.0f;
  const float htan = fminf(fmaxf(x, -1.0f), 1.0f);
  const float lky  = (x >= 0.0f) ? x : 0.01f * x;
  const float ssn  = x * rcpf(1.0f + ax);
  float r = aw[0] * ssh;
  r = fmaf(aw[1],  relu,   r);
  r = fmaf(aw[2],  x,      r);
  r = fmaf(aw[3],  gelu,   r);
  r = fmaf(aw[4],  elu,    r);
  r = fmaf(aw[5],  hsh,    r);
  r = fmaf(aw[6],  htan,   r);
  r = fmaf(aw[7],  x * t6, r);
  r = fmaf(aw[8],  selu,   r);
  r = fmaf(aw[9],  elu,    r);   // celu(alpha=1) == elu
  r = fmaf(aw[10], lky,    r);
  r = fmaf(aw[11], lsg,    r);
  r = fmaf(aw[12], x - th, r);
  r = fmaf(aw[13], ssn,    r);
  r = fmaf(aw[14], sp,     r);
  r = fmaf(aw[15], th,     r);
  r = fmaf(aw[16], sig,    r);
  r = fmaf(aw[17], t6,     r);
  r = fmaf(aw[18], x * sig, r);
  r = fmaf(aw[19], mish,   r);
  return r;
}

// ---------------- fused prep: hi/lo splits of W (and W^T) and x ----------------
__global__ void k_prep(const float* __restrict__ W, const float* __restrict__ x,
                       bf16_t* __restrict__ Whi, bf16_t* __restrict__ Wlo,
                       bf16_t* __restrict__ Wth, bf16_t* __restrict__ Wtl,
                       bf16_t* __restrict__ xh, bf16_t* __restrict__ xl) {
  int i = blockIdx.x * 256 + threadIdx.x;
  if (i < 512 * 1024) {
    float w = W[i];
    bf16_t h = __float2bfloat16(w);
    bf16_t l = __float2bfloat16(w - __bfloat162float(h));
    Whi[i] = h; Wlo[i] = l;
    int n = i >> 10, hc = i & 1023;
    Wth[hc * 512 + n] = h; Wtl[hc * 512 + n] = l;
  }
  int j = i - 512 * 1024;
  if (j >= 0 && j < 4096 * 512) {
    float v = x[j];
    bf16_t h = __float2bfloat16(v);
    xh[j] = h;
    xl[j] = __float2bfloat16(v - __bfloat162float(h));
  }
}

// ---------------- L pipeline: MFMA hi/lo squaring -------
// 9 squarings: Rayleigh mode weight (lam2/lam1)^512 ~ e^{-8} -> rel err <1e-4.
template <int KDIM, bool FIRST, bool WF32>
__global__ __launch_bounds__(256) void k_sqm(
    const bf16_t* __restrict__ Xhi, const bf16_t* __restrict__ Xlo,
    bf16_t* __restrict__ Chi, bf16_t* __restrict__ Clo,
    float* __restrict__ Cf,
    const float* __restrict__ pin, float* __restrict__ pout) {
  __shared__ __align__(16) ushort_t Ah[2][32 * 64], Al[2][32 * 64],
                                    Bh[2][32 * 64], Bl[2][32 * 64];
  __shared__ float red[4];
  const int tid = threadIdx.x, lane = tid & 63, wave = tid >> 6;
  const int wm = wave >> 1, wn = wave & 1;
  const int i0 = blockIdx.x * 32, j0 = blockIdx.y * 32;
  const int bid = blockIdx.y * gridDim.x + blockIdx.x;
  const int r16 = lane & 15, kg = lane >> 4;

  float s = 1.0f;
  if constexpr (!FIRST) {
    float v = pin[tid];
    for (int off = 32; off; off >>= 1) v += __shfl_down(v, off, 64);
    if ((tid & 63) == 0) red[tid >> 6] = v;
    __syncthreads();
    s = 1.0f / (red[0] + red[1] + red[2] + red[3]);
    __syncthreads();
  }

  const int row = tid >> 3;
  const int srcc = (((tid & 7) ^ (row & 7)) << 3);
  const long abase = (long)(i0 + row) * KDIM + srcc;
  const long bbase = (long)(j0 + row) * KDIM + srcc;
  const int ldst = tid * 8;

  auto stage = [&](int buf, int kt) {
    gload_lds16(Xhi + abase + kt, &Ah[buf][ldst]);
    gload_lds16(Xlo + abase + kt, &Al[buf][ldst]);
    gload_lds16(Xhi + bbase + kt, &Bh[buf][ldst]);
    gload_lds16(Xlo + bbase + kt, &Bl[buf][ldst]);
  };

  f32x4 acc = {};
  constexpr int NT = KDIM / 64;
  stage(0, 0);
  __syncthreads();
  for (int t = 0; t < NT; ++t) {
    if (t + 1 < NT) stage((t + 1) & 1, (t + 1) * 64);
    const int b = t & 1;
    const int ra = wm * 16 + r16, rb = wn * 16 + r16;
#pragma unroll
    for (int kk = 0; kk < 64; kk += 32) {
      int oa = ra * 64 + ((kk + kg * 8) ^ ((ra & 7) * 8));
      int ob = rb * 64 + ((kk + kg * 8) ^ ((rb & 7) * 8));
      bf16x8 ah = *(const bf16x8*)&Ah[b][oa];
      bf16x8 al = *(const bf16x8*)&Al[b][oa];
      bf16x8 bh = *(const bf16x8*)&Bh[b][ob];
      bf16x8 bl = *(const bf16x8*)&Bl[b][ob];
      acc = __builtin_amdgcn_mfma_f32_16x16x32_bf16(ah, bh, acc, 0, 0, 0);
      acc = __builtin_amdgcn_mfma_f32_16x16x32_bf16(ah, bl, acc, 0, 0, 0);
      acc = __builtin_amdgcn_mfma_f32_16x16x32_bf16(al, bh, acc, 0, 0, 0);
    }
    __syncthreads();
  }

  float fro = 0.0f;
#pragma unroll
  for (int r = 0; r < 4; ++r) {
    float c = acc[r] * s;
    int orow = i0 + wm * 16 + (lane >> 4) * 4 + r;
    int ocol = j0 + wn * 16 + r16;
    int idx = orow * 512 + ocol;
    bf16_t h = __float2bfloat16(c);
    Chi[idx] = h;
    Clo[idx] = __float2bfloat16(c - __bfloat162float(h));
    if constexpr (WF32) Cf[idx] = c;
    fro = fmaf(c, c, fro);
  }
  for (int off = 32; off; off >>= 1) fro += __shfl_down(fro, off, 64);
  if ((tid & 63) == 0) red[tid >> 6] = fro;
  __syncthreads();
  if (tid == 0) pout[bid] = red[0] + red[1] + red[2] + red[3];
}

// ---------------- G = W^T W (1024x1024), f32-accurate, rounded once to bf16 --
__global__ __launch_bounds__(256) void k_G(const bf16_t* __restrict__ Xhi,
                                           const bf16_t* __restrict__ Xlo,
                                           bf16_t* __restrict__ G) {
  __shared__ __align__(16) ushort_t Ah[2][32 * 64], Al[2][32 * 64],
                                    Bh[2][32 * 64], Bl[2][32 * 64];
  const int tid = threadIdx.x, lane = tid & 63, wave = tid >> 6;
  const int wm = wave >> 1, wn = wave & 1;
  const int i0 = blockIdx.x * 32, j0 = blockIdx.y * 32;
  const int r16 = lane & 15, kg = lane >> 4;
  const int row = tid >> 3;
  const int srcc = (((tid & 7) ^ (row & 7)) << 3);
  const long abase = (long)(i0 + row) * 512 + srcc;
  const long bbase = (long)(j0 + row) * 512 + srcc;
  const int ldst = tid * 8;

  auto stage = [&](int buf, int kt) {
    gload_lds16(Xhi + abase + kt, &Ah[buf][ldst]);
    gload_lds16(Xlo + abase + kt, &Al[buf][ldst]);
    gload_lds16(Xhi + bbase + kt, &Bh[buf][ldst]);
    gload_lds16(Xlo + bbase + kt, &Bl[buf][ldst]);
  };

  f32x4 acc = {};
  stage(0, 0);
  __syncthreads();
  for (int t = 0; t < 8; ++t) {
    if (t + 1 < 8) stage((t + 1) & 1, (t + 1) * 64);
    const int b = t & 1;
    const int ra = wm * 16 + r16, rb = wn * 16 + r16;
#pragma unroll
    for (int kk = 0; kk < 64; kk += 32) {
      int oa = ra * 64 + ((kk + kg * 8) ^ ((ra & 7) * 8));
      int ob = rb * 64 + ((kk + kg * 8) ^ ((rb & 7) * 8));
      bf16x8 ah = *(const bf16x8*)&Ah[b][oa];
      bf16x8 al = *(const bf16x8*)&Al[b][oa];
      bf16x8 bh = *(const bf16x8*)&Bh[b][ob];
      bf16x8 bl = *(const bf16x8*)&Bl[b][ob];
      acc = __builtin_amdgcn_mfma_f32_16x16x32_bf16(ah, bh, acc, 0, 0, 0);
      acc = __builtin_amdgcn_mfma_f32_16x16x32_bf16(ah, bl, acc, 0, 0, 0);
      acc = __builtin_amdgcn_mfma_f32_16x16x32_bf16(al, bh, acc, 0, 0, 0);
    }
    __syncthreads();
  }
#pragma unroll
  for (int r = 0; r < 4; ++r) {
    int orow = i0 + wm * 16 + (lane >> 4) * 4 + r;
    int ocol = j0 + wn * 16 + r16;
    G[orow * 1024 + ocol] = __float2bfloat16(acc[r]);
  }
}

// ---------------- xW = x·W (4096x1024, f32, exact via 3-term hi/lo) ----------
__global__ __launch_bounds__(256) void k_xw(const bf16_t* __restrict__ xh_,
                                            const bf16_t* __restrict__ xl_,
                                            const bf16_t* __restrict__ Bh_,
                                            const bf16_t* __restrict__ Bl_,
                                            float* __restrict__ out) {
  __shared__ __align__(16) ushort_t Axh[2][64 * 64], Axl[2][64 * 64],
                                    Bwh[2][64 * 64], Bwl[2][64 * 64];
  const int tid = threadIdx.x, lane = tid & 63, wave = tid >> 6;
  const int wm = wave >> 1, wn = wave & 1;
  const int m0 = blockIdx.x * 64, n0 = blockIdx.y * 64;
  const int r16 = lane & 15, kg = lane >> 4;

  auto stage = [&](int buf, int kt) {
#pragma unroll
    for (int q = 0; q < 2; ++q) {
      int lin = (tid + q * 256) * 8;
      int row = lin >> 6;
      int col = ((((lin >> 3) & 7) ^ (row & 7)) << 3);
      gload_lds16(xh_ + (long)(m0 + row) * 512 + kt + col, &Axh[buf][lin]);
      gload_lds16(xl_ + (long)(m0 + row) * 512 + kt + col, &Axl[buf][lin]);
      gload_lds16(Bh_ + (long)(n0 + row) * 512 + kt + col, &Bwh[buf][lin]);
      gload_lds16(Bl_ + (long)(n0 + row) * 512 + kt + col, &Bwl[buf][lin]);
    }
  };

  f32x4 acc[2][2] = {};
  stage(0, 0);
  __syncthreads();
  for (int t = 0; t < 8; ++t) {
    if (t + 1 < 8) stage((t + 1) & 1, (t + 1) * 64);
    const int b = t & 1;
#pragma unroll
    for (int kk = 0; kk < 64; kk += 32) {
      bf16x8 ah[2], al[2], bh[2], bl[2];
#pragma unroll
      for (int f = 0; f < 2; ++f) {
        int ra = wm * 32 + f * 16 + r16;
        int rb = wn * 32 + f * 16 + r16;
        int oa = ra * 64 + ((kk + kg * 8) ^ ((ra & 7) * 8));
        int ob = rb * 64 + ((kk + kg * 8) ^ ((rb & 7) * 8));
        ah[f] = *(const bf16x8*)&Axh[b][oa];
        al[f] = *(const bf16x8*)&Axl[b][oa];
        bh[f] = *(const bf16x8*)&Bwh[b][ob];
        bl[f] = *(const bf16x8*)&Bwl[b][ob];
      }
#pragma unroll
      for (int i = 0; i < 2; ++i)
#pragma unroll
        for (int j = 0; j < 2; ++j) {
          acc[i][j] = __builtin_amdgcn_mfma_f32_16x16x32_bf16(ah[i], bh[j], acc[i][j], 0, 0, 0);
          acc[i][j] = __builtin_amdgcn_mfma_f32_16x16x32_bf16(ah[i], bl[j], acc[i][j], 0, 0, 0);
          acc[i][j] = __builtin_amdgcn_mfma_f32_16x16x32_bf16(al[i], bh[j], acc[i][j], 0, 0, 0);
        }
    }
    __syncthreads();
  }
#pragma unroll
  for (int i = 0; i < 2; ++i)
#pragma unroll
    for (int j = 0; j < 2; ++j)
#pragma unroll
      for (int r = 0; r < 4; ++r) {
        int row = m0 + wm * 32 + i * 16 + (lane >> 4) * 4 + r;
        int col = n0 + wn * 32 + j * 16 + r16;
        out[(long)row * 1024 + col] = acc[i][j][r];
      }
}

// ---------------- Rayleigh num/den partials ----------------
__global__ __launch_bounds__(256) void k_dot(const float* __restrict__ A0,
                                             const float* __restrict__ B,
                                             float* __restrict__ numP,
                                             float* __restrict__ denP) {
  __shared__ float redn[4], redd[4];
  const int tid = threadIdx.x;
  const int idx4 = blockIdx.x * 256 + tid;
  const f32x4 a = ((const f32x4*)A0)[idx4];
  const f32x4 b = ((const f32x4*)B)[idx4];
  float nv = a[0]*b[0] + a[1]*b[1] + a[2]*b[2] + a[3]*b[3];
  float dv = 0.0f;
#pragma unroll
  for (int q = 0; q < 4; ++q) {
    int i = idx4 * 4 + q;
    if ((i >> 9) == (i & 511)) dv += b[q];
  }
  for (int off = 32; off; off >>= 1) {
    nv += __shfl_down(nv, off, 64);
    dv += __shfl_down(dv, off, 64);
  }
  if ((tid & 63) == 0) { redn[tid >> 6] = nv; redd[tid >> 6] = dv; }
  __syncthreads();
  if (tid == 0) {
    numP[blockIdx.x] = redn[0] + redn[1] + redn[2] + redn[3];
    denP[blockIdx.x] = redd[0] + redd[1] + redd[2] + redd[3];
  }
}

__global__ __launch_bounds__(256) void k_setup(const float* __restrict__ alpha,
                                               const float* __restrict__ beta,
                                               const float* __restrict__ numP,
                                               const float* __restrict__ denP,
                                               float* __restrict__ params) {
  __shared__ float redn[4], redd[4];
  __shared__ float Lsh;
  const int tid = threadIdx.x;
  float nv = numP[tid], dv = denP[tid];
  for (int off = 32; off; off >>= 1) {
    nv += __shfl_down(nv, off, 64);
    dv += __shfl_down(dv, off, 64);
  }
  if ((tid & 63) == 0) { redn[tid >> 6] = nv; redd[tid >> 6] = dv; }
  __syncthreads();
  if (tid == 0)
    Lsh = (redn[0] + redn[1] + redn[2] + redn[3]) /
          (redd[0] + redd[1] + redd[2] + redd[3]);
  __syncthreads();
  const int t = tid;
  if (t >= 10) return;
  float L = Lsh;
  float invL = 1.0f / L;
  float lam = 0.001f * invL;
  const float* a = alpha + t * 20;
  float mx = a[0];
  for (int k = 1; k < 20; ++k) mx = fmaxf(mx, a[k]);
  float e[20], ssum = 0.0f;
  for (int k = 0; k < 20; ++k) { e[k] = expf(a[k] - mx); ssum += e[k]; }
  float inv = 1.0f / ssum;
  float* P = params + t * 32;
  for (int k = 0; k < 20; ++k) P[k] = e[k] * inv;
  float b0 = beta[t * 2], b1 = beta[t * 2 + 1];
  float bm = fmaxf(b0, b1);
  float eb0 = expf(b0 - bm), eb1 = expf(b1 - bm);
  float bw0 = eb0 / (eb0 + eb1);
  P[20] = ((float)(t + 1) / (float)(t + 4)) * bw0;  // c_{i+1} * bw0_i
  P[21] = invL;
  P[22] = lam;
  P[23] = L;
}

// ---------------- iteration 0: zaux=0 -> zg = xW*invL (pure elementwise) -----
__global__ __launch_bounds__(256) void k_it0(const float* __restrict__ xW,
                                             bf16_t* __restrict__ zauxB,
                                             bf16_t* __restrict__ zB,
                                             const float* __restrict__ prm) {
  const int i = blockIdx.x * 256 + threadIdx.x;   // f32x4 index, 4096*1024/4
  const float d = prm[20], invL = prm[21], lam = prm[22];
  float aw[20];
#pragma unroll
  for (int k = 0; k < 20; ++k) aw[k] = prm[k];
  f32x4 v = ((const f32x4*)xW)[i];
#pragma unroll
  for (int r = 0; r < 4; ++r) {
    float zop = act_mix(v[r] * invL, aw, lam);
    zB[i * 4 + r] = __float2bfloat16(zop);
    zauxB[i * 4 + r] = __float2bfloat16(zop * (1.0f + d));  // zold = 0
  }
}

// ---------------- main iteration: acc = zaux·G; epilogue -------------------
// Counted-vmcnt 2-buffer pipeline (T4): stage = 6 gload_lds per wave;
// {compute(t); lgkmcnt(0); barrier; stage(t+2); vmcnt(6); barrier}.
// vmcnt NEVER drained to 0 in the steady loop (round-5 lesson: __syncthreads'
// vmcnt(0) drain exposed ~700cy HBM latency per K-tile = 40us of stall).
template <bool LAST>
__global__ __launch_bounds__(256) void k_iter(const bf16_t* __restrict__ A,  // zauxB
                                              const bf16_t* __restrict__ G,
                                              const float* __restrict__ xW,
                                              bf16_t* zauxB, bf16_t* zB,
                                              float* zio,
                                              const float* __restrict__ prm) {
  __shared__ __align__(16) ushort_t As[2][128 * 64], Bs[2][64 * 64];
  const int tid = threadIdx.x, lane = tid & 63, wave = tid >> 6;
  const int wm = wave >> 1, wn = wave & 1;
  const int bid = blockIdx.x;
  const int swz = (bid & 7) * 64 + (bid >> 3);    // XCD swizzle (512 % 8 == 0)
  const int m0 = (swz >> 4) * 128, n0 = (swz & 15) * 64;
  const int r16 = lane & 15, kg = lane >> 4;

  auto stage = [&](int buf, int kt) {             // exactly 6 gload_lds / wave
#pragma unroll
    for (int q = 0; q < 4; ++q) {
      int lin = (tid + q * 256) * 8;
      int row = lin >> 6;
      int col = ((((lin >> 3) & 7) ^ (row & 7)) << 3);
      gload_lds16(A + (long)(m0 + row) * 1024 + kt + col, &As[buf][lin]);
      if (q < 2)
        gload_lds16(G + (long)(n0 + row) * 1024 + kt + col, &Bs[buf][lin]);
    }
  };

  f32x4 acc[4][2] = {};
  auto compute = [&](int b) {
#pragma unroll
    for (int kk = 0; kk < 64; kk += 32) {
      bf16x8 a[4], bb[2];
#pragma unroll
      for (int f = 0; f < 4; ++f) {
        int ra = wm * 64 + f * 16 + r16;
        a[f] = *(const bf16x8*)&As[b][ra * 64 + ((kk + kg * 8) ^ ((ra & 7) * 8))];
      }
#pragma unroll
      for (int f = 0; f < 2; ++f) {
        int rb = wn * 32 + f * 16 + r16;
        bb[f] = *(const bf16x8*)&Bs[b][rb * 64 + ((kk + kg * 8) ^ ((rb & 7) * 8))];
      }
#pragma unroll
      for (int i = 0; i < 4; ++i)
#pragma unroll
        for (int j = 0; j < 2; ++j)
          acc[i][j] = __builtin_amdgcn_mfma_f32_16x16x32_bf16(a[i], bb[j], acc[i][j], 0, 0, 0);
    }
  };

  // prologue: stage tiles 0 and 1 (12 loads/wave in flight)
  stage(0, 0);
  stage(1, 64);
  asm volatile("s_waitcnt vmcnt(6)" ::: "memory");   // tile 0 landed everywhere (own)
  __builtin_amdgcn_s_barrier();                      // ...and by all waves
  __builtin_amdgcn_sched_barrier(0);

  for (int t = 0; t < 16; ++t) {
    compute(t & 1);
    if (t == 15) break;
    // all this wave's ds_reads complete before anyone overwrites buf[t&1]
    asm volatile("s_waitcnt lgkmcnt(0)" ::: "memory");
    __builtin_amdgcn_sched_barrier(0);
    __builtin_amdgcn_s_barrier();
    if (t + 2 < 16) {
      stage(t & 1, (t + 2) * 64);                    // overwrite just-freed buf
      asm volatile("s_waitcnt vmcnt(6)" ::: "memory"); // tile t+1 done; t+2 in flight
    } else {
      asm volatile("s_waitcnt vmcnt(0)" ::: "memory"); // only tile 15 outstanding
    }
    __builtin_amdgcn_s_barrier();
    __builtin_amdgcn_sched_barrier(0);
  }
  __builtin_amdgcn_sched_barrier(0);

  const float d_i = prm[20];
  const float invL = prm[21];
  const float lam = prm[22];
  float aw[20];
#pragma unroll
  for (int k = 0; k < 20; ++k) aw[k] = prm[k];

  // epilogue: issue ALL operand loads first (ILP), then compute+store
  float xv[4][2][4], av[4][2][4], zv[4][2][4];
#pragma unroll
  for (int i = 0; i < 4; ++i)
#pragma unroll
    for (int j = 0; j < 2; ++j)
#pragma unroll
      for (int r = 0; r < 4; ++r) {
        int row = m0 + wm * 64 + i * 16 + (lane >> 4) * 4 + r;
        int col = n0 + wn * 32 + j * 16 + r16;
        long idx = (long)row * 1024 + col;
        xv[i][j][r] = xW[idx];
        av[i][j][r] = __bfloat162float(A[idx]);
        if (!LAST) zv[i][j][r] = __bfloat162float(zB[idx]);
      }
#pragma unroll
  for (int i = 0; i < 4; ++i)
#pragma unroll
    for (int j = 0; j < 2; ++j)
#pragma unroll
      for (int r = 0; r < 4; ++r) {
        int row = m0 + wm * 64 + i * 16 + (lane >> 4) * 4 + r;
        int col = n0 + wn * 32 + j * 16 + r16;
        long idx = (long)row * 1024 + col;
        float zg = fmaf(xv[i][j][r] - acc[i][j][r], invL, av[i][j][r]);
        float zop = act_mix(zg, aw, lam);
        if (LAST) {
          zio[idx] = zop;
        } else {
          zB[idx] = __float2bfloat16(zop);
          zauxB[idx] = __float2bfloat16(fmaf(d_i, zop - zv[i][j][r], zop));
        }
      }
}

// ---------------- orchestration ----------------
extern "C" void kernel_launch(void* const* d_in, const int* in_sizes, int n_in,
                              void* d_out, int out_size, void* d_ws, size_t ws_size,
                              hipStream_t stream) {
  const float* x     = (const float*)d_in[0];
  const float* W     = (const float*)d_in[1];
  const float* alpha = (const float*)d_in[2];
  const float* beta  = (const float*)d_in[3];
  float* zout = (float*)d_out;

  char* ws = (char*)d_ws;
  const size_t MB = 1u << 20;
  float* pb[11];
  for (int k = 0; k < 11; ++k) pb[k] = (float*)(ws + (size_t)k * 1024);
  float* numP   = (float*)(ws + 12 * 1024);
  float* denP   = (float*)(ws + 13 * 1024);
  float* params = (float*)(ws + 14 * 1024);
  const size_t HDR = 32768;
  float*  A0f  = (float*)(ws + HDR);                 // 1 MB
  float*  Bf   = (float*)(ws + HDR + 1 * MB);        // 1 MB
  bf16_t* H0   = (bf16_t*)(ws + HDR + 2 * MB);       // 0.5 MB
  bf16_t* L0   = (bf16_t*)(ws + HDR + 2 * MB + 512 * 1024);
  bf16_t* H1   = (bf16_t*)(ws + HDR + 3 * MB);
  bf16_t* L1   = (bf16_t*)(ws + HDR + 3 * MB + 512 * 1024);
  bf16_t* Whi  = (bf16_t*)(ws + HDR + 4 * MB);       // 1 MB
  bf16_t* Wlo  = (bf16_t*)(ws + HDR + 5 * MB);       // 1 MB
  bf16_t* Wth  = (bf16_t*)(ws + HDR + 6 * MB);       // 1 MB
  bf16_t* Wtl  = (bf16_t*)(ws + HDR + 7 * MB);       // 1 MB
  bf16_t* Gm   = (bf16_t*)(ws + HDR + 8 * MB);       // 2 MB
  bf16_t* xh   = (bf16_t*)(ws + HDR + 10 * MB);      // 4 MB
  bf16_t* xl   = (bf16_t*)(ws + HDR + 14 * MB);      // 4 MB
  float*  xW   = (float*)(ws + HDR + 18 * MB);       // 16 MB
  bf16_t* zauxB= (bf16_t*)(ws + HDR + 34 * MB);      // 8 MB
  bf16_t* zB   = (bf16_t*)(ws + HDR + 42 * MB);      // 8 MB  (~50 MB of 256 MB)

  k_prep<<<10240, 256, 0, stream>>>(W, x, Whi, Wlo, Wth, Wtl, xh, xl);

  // G and xW (L-independent)
  k_G<<<dim3(32, 32), 256, 0, stream>>>(Wth, Wtl, Gm);
  k_xw<<<dim3(64, 16), 256, 0, stream>>>(xh, xl, Wth, Wtl, xW);

  // L: A0 = W*W^T (hi/lo MFMA), 9 normalized squarings, Rayleigh via traces
  k_sqm<1024, true, true><<<dim3(16, 16), 256, 0, stream>>>(
      Whi, Wlo, H0, L0, A0f, nullptr, pb[0]);
  bf16_t* Hs[2] = {H0, H1};
  bf16_t* Ls[2] = {L0, L1};
  int pp = 0;
  for (int k = 0; k < 9; ++k) {
    if (k == 8)
      k_sqm<512, false, true><<<dim3(16, 16), 256, 0, stream>>>(
          Hs[pp], Ls[pp], Hs[pp ^ 1], Ls[pp ^ 1], Bf, pb[k], pb[k + 1]);
    else
      k_sqm<512, false, false><<<dim3(16, 16), 256, 0, stream>>>(
          Hs[pp], Ls[pp], Hs[pp ^ 1], Ls[pp ^ 1], nullptr, pb[k], pb[k + 1]);
    pp ^= 1;
  }
  k_dot<<<256, 256, 0, stream>>>(A0f, Bf, numP, denP);
  k_setup<<<1, 256, 0, stream>>>(alpha, beta, numP, denP, params);

  // iter 0 (zaux = 0): pure elementwise
  k_it0<<<4096, 256, 0, stream>>>(xW, zauxB, zB, params);

  // iters 1..9: single fused GEMM+epilogue each
  for (int i = 1; i < 9; ++i)
    k_iter<false><<<512, 256, 0, stream>>>(zauxB, Gm, xW, zauxB, zB, zout,
                                           params + i * 32);
  k_iter<true><<<512, 256, 0, stream>>>(zauxB, Gm, xW, zauxB, zB, zout,
                                        params + 9 * 32);
}

// Round 7
// 381.132 us; speedup vs baseline: 3.3566x; 1.2355x over previous
//
#include <hip/hip_runtime.h>
#include <hip/hip_bf16.h>

#define DI __device__ __forceinline__

typedef float f32x4 __attribute__((ext_vector_type(4)));
typedef __bf16 bf16x8 __attribute__((ext_vector_type(8)));
using bf16_t = __hip_bfloat16;
using ushort_t = unsigned short;

// ---------------- async global->LDS (16B per lane) ----------------
DI void gload_lds16(const void* g, void* l) {
  __builtin_amdgcn_global_load_lds(
      (const __attribute__((address_space(1))) void*)g,
      (__attribute__((address_space(3))) void*)l, 16, 0, 0);
}

DI float rcpf(float x) { return __builtin_amdgcn_rcpf(x); }

// ---------------- 20-way weighted activation mixture ----------------
DI float act_mix(float x, const float* aw, float lam) {
  const float ax  = fabsf(x);
  const float en  = __expf(-ax);        // e^{-|x|} in (0,1]
  const float en2 = en * en;            // e^{-2|x|}
  const float i1  = rcpf(1.0f + en);
  const float sig = (x >= 0.0f) ? i1 : en * i1;            // sigmoid
  const float th  = copysignf((1.0f - en2) * rcpf(1.0f + en2), x); // tanh
  const float l1p = __logf(1.0f + en);
  const float sp  = fmaxf(x, 0.0f) + l1p;                  // softplus
  const float lsg = fminf(x, 0.0f) - l1p;                  // logsigmoid
  const float q   = ((x >= 0.0f) ? en2 : 1.0f) * (i1 * i1);// e^{-2*softplus}
  const float mish = x * (1.0f - q) * rcpf(1.0f + q);
  // gelu exact via A&S 7.1.26 erf approx (|err|<=1.5e-7)
  const float u  = 0.7071067811865476f * x;
  const float au = fabsf(u);
  const float t  = rcpf(1.0f + 0.3275911f * au);
  float poly = fmaf(t, 1.061405429f, -1.453152027f);
  poly = fmaf(t, poly, 1.421413741f);
  poly = fmaf(t, poly, -0.284496736f);
  poly = fmaf(t, poly, 0.254829592f);
  poly *= t;
  const float erfa = 1.0f - poly * __expf(-u * u);
  const float gelu = 0.5f * x * (1.0f + copysignf(erfa, x));
  const float em1  = en - 1.0f;                            // e^x-1 for x<=0
  const float elu  = (x > 0.0f) ? x : em1;
  const float selu = (x > 0.0f) ? 1.0507009873554805f * x : 1.7580993408473766f * em1;
  const float relu = fmaxf(x, 0.0f);
  const float t6   = fminf(fmaxf(x + 3.0f, 0.0f), 6.0f) * 0.16666666666666666f;
  const float ssh  = (x > lam) ? (x - lam) : ((x < -lam) ? (x + lam) : 0.0f);
  const float hsh  = (ax > lam) ? x : 0.0f;
  const float htan = fminf(fmaxf(x, -1.0f), 1.0f);
  const float lky  = (x >= 0.0f) ? x : 0.01f * x;
  const float ssn  = x * rcpf(1.0f + ax);
  float r = aw[0] * ssh;
  r = fmaf(aw[1],  relu,   r);
  r = fmaf(aw[2],  x,      r);
  r = fmaf(aw[3],  gelu,   r);
  r = fmaf(aw[4],  elu,    r);
  r = fmaf(aw[5],  hsh,    r);
  r = fmaf(aw[6],  htan,   r);
  r = fmaf(aw[7],  x * t6, r);
  r = fmaf(aw[8],  selu,   r);
  r = fmaf(aw[9],  elu,    r);   // celu(alpha=1) == elu
  r = fmaf(aw[10], lky,    r);
  r = fmaf(aw[11], lsg,    r);
  r = fmaf(aw[12], x - th, r);
  r = fmaf(aw[13], ssn,    r);
  r = fmaf(aw[14], sp,     r);
  r = fmaf(aw[15], th,     r);
  r = fmaf(aw[16], sig,    r);
  r = fmaf(aw[17], t6,     r);
  r = fmaf(aw[18], x * sig, r);
  r = fmaf(aw[19], mish,   r);
  return r;
}

// ---------------- fused prep: hi/lo splits of W (and W^T) and x ----------------
__global__ void k_prep(const float* __restrict__ W, const float* __restrict__ x,
                       bf16_t* __restrict__ Whi, bf16_t* __restrict__ Wlo,
                       bf16_t* __restrict__ Wth, bf16_t* __restrict__ Wtl,
                       bf16_t* __restrict__ xh, bf16_t* __restrict__ xl) {
  int i = blockIdx.x * 256 + threadIdx.x;
  if (i < 512 * 1024) {
    float w = W[i];
    bf16_t h = __float2bfloat16(w);
    bf16_t l = __float2bfloat16(w - __bfloat162float(h));
    Whi[i] = h; Wlo[i] = l;
    int n = i >> 10, hc = i & 1023;
    Wth[hc * 512 + n] = h; Wtl[hc * 512 + n] = l;
  }
  int j = i - 512 * 1024;
  if (j >= 0 && j < 4096 * 512) {
    float v = x[j];
    bf16_t h = __float2bfloat16(v);
    xh[j] = h;
    xl[j] = __float2bfloat16(v - __bfloat162float(h));
  }
}

// ---------------- L pipeline: MFMA hi/lo squaring -------
// 9 squarings: Rayleigh mode weight (lam2/lam1)^512 ~ e^{-8} -> rel err <1e-4.
template <int KDIM, bool FIRST, bool WF32>
__global__ __launch_bounds__(256) void k_sqm(
    const bf16_t* __restrict__ Xhi, const bf16_t* __restrict__ Xlo,
    bf16_t* __restrict__ Chi, bf16_t* __restrict__ Clo,
    float* __restrict__ Cf,
    const float* __restrict__ pin, float* __restrict__ pout) {
  __shared__ __align__(16) ushort_t Ah[2][32 * 64], Al[2][32 * 64],
                                    Bh[2][32 * 64], Bl[2][32 * 64];
  __shared__ float red[4];
  const int tid = threadIdx.x, lane = tid & 63, wave = tid >> 6;
  const int wm = wave >> 1, wn = wave & 1;
  const int i0 = blockIdx.x * 32, j0 = blockIdx.y * 32;
  const int bid = blockIdx.y * gridDim.x + blockIdx.x;
  const int r16 = lane & 15, kg = lane >> 4;

  float s = 1.0f;
  if constexpr (!FIRST) {
    float v = pin[tid];
    for (int off = 32; off; off >>= 1) v += __shfl_down(v, off, 64);
    if ((tid & 63) == 0) red[tid >> 6] = v;
    __syncthreads();
    s = 1.0f / (red[0] + red[1] + red[2] + red[3]);
    __syncthreads();
  }

  const int row = tid >> 3;
  const int srcc = (((tid & 7) ^ (row & 7)) << 3);
  const long abase = (long)(i0 + row) * KDIM + srcc;
  const long bbase = (long)(j0 + row) * KDIM + srcc;
  const int ldst = tid * 8;

  auto stage = [&](int buf, int kt) {
    gload_lds16(Xhi + abase + kt, &Ah[buf][ldst]);
    gload_lds16(Xlo + abase + kt, &Al[buf][ldst]);
    gload_lds16(Xhi + bbase + kt, &Bh[buf][ldst]);
    gload_lds16(Xlo + bbase + kt, &Bl[buf][ldst]);
  };

  f32x4 acc = {};
  constexpr int NT = KDIM / 64;
  stage(0, 0);
  __syncthreads();
  for (int t = 0; t < NT; ++t) {
    if (t + 1 < NT) stage((t + 1) & 1, (t + 1) * 64);
    const int b = t & 1;
    const int ra = wm * 16 + r16, rb = wn * 16 + r16;
#pragma unroll
    for (int kk = 0; kk < 64; kk += 32) {
      int oa = ra * 64 + ((kk + kg * 8) ^ ((ra & 7) * 8));
      int ob = rb * 64 + ((kk + kg * 8) ^ ((rb & 7) * 8));
      bf16x8 ah = *(const bf16x8*)&Ah[b][oa];
      bf16x8 al = *(const bf16x8*)&Al[b][oa];
      bf16x8 bh = *(const bf16x8*)&Bh[b][ob];
      bf16x8 bl = *(const bf16x8*)&Bl[b][ob];
      acc = __builtin_amdgcn_mfma_f32_16x16x32_bf16(ah, bh, acc, 0, 0, 0);
      acc = __builtin_amdgcn_mfma_f32_16x16x32_bf16(ah, bl, acc, 0, 0, 0);
      acc = __builtin_amdgcn_mfma_f32_16x16x32_bf16(al, bh, acc, 0, 0, 0);
    }
    __syncthreads();
  }

  float fro = 0.0f;
#pragma unroll
  for (int r = 0; r < 4; ++r) {
    float c = acc[r] * s;
    int orow = i0 + wm * 16 + (lane >> 4) * 4 + r;
    int ocol = j0 + wn * 16 + r16;
    int idx = orow * 512 + ocol;
    bf16_t h = __float2bfloat16(c);
    Chi[idx] = h;
    Clo[idx] = __float2bfloat16(c - __bfloat162float(h));
    if constexpr (WF32) Cf[idx] = c;
    fro = fmaf(c, c, fro);
  }
  for (int off = 32; off; off >>= 1) fro += __shfl_down(fro, off, 64);
  if ((tid & 63) == 0) red[tid >> 6] = fro;
  __syncthreads();
  if (tid == 0) pout[bid] = red[0] + red[1] + red[2] + red[3];
}

// ---------------- G = W^T W (1024x1024), f32-accurate, rounded once to bf16 --
__global__ __launch_bounds__(256) void k_G(const bf16_t* __restrict__ Xhi,
                                           const bf16_t* __restrict__ Xlo,
                                           bf16_t* __restrict__ G) {
  __shared__ __align__(16) ushort_t Ah[2][32 * 64], Al[2][32 * 64],
                                    Bh[2][32 * 64], Bl[2][32 * 64];
  const int tid = threadIdx.x, lane = tid & 63, wave = tid >> 6;
  const int wm = wave >> 1, wn = wave & 1;
  const int i0 = blockIdx.x * 32, j0 = blockIdx.y * 32;
  const int r16 = lane & 15, kg = lane >> 4;
  const int row = tid >> 3;
  const int srcc = (((tid & 7) ^ (row & 7)) << 3);
  const long abase = (long)(i0 + row) * 512 + srcc;
  const long bbase = (long)(j0 + row) * 512 + srcc;
  const int ldst = tid * 8;

  auto stage = [&](int buf, int kt) {
    gload_lds16(Xhi + abase + kt, &Ah[buf][ldst]);
    gload_lds16(Xlo + abase + kt, &Al[buf][ldst]);
    gload_lds16(Xhi + bbase + kt, &Bh[buf][ldst]);
    gload_lds16(Xlo + bbase + kt, &Bl[buf][ldst]);
  };

  f32x4 acc = {};
  stage(0, 0);
  __syncthreads();
  for (int t = 0; t < 8; ++t) {
    if (t + 1 < 8) stage((t + 1) & 1, (t + 1) * 64);
    const int b = t & 1;
    const int ra = wm * 16 + r16, rb = wn * 16 + r16;
#pragma unroll
    for (int kk = 0; kk < 64; kk += 32) {
      int oa = ra * 64 + ((kk + kg * 8) ^ ((ra & 7) * 8));
      int ob = rb * 64 + ((kk + kg * 8) ^ ((rb & 7) * 8));
      bf16x8 ah = *(const bf16x8*)&Ah[b][oa];
      bf16x8 al = *(const bf16x8*)&Al[b][oa];
      bf16x8 bh = *(const bf16x8*)&Bh[b][ob];
      bf16x8 bl = *(const bf16x8*)&Bl[b][ob];
      acc = __builtin_amdgcn_mfma_f32_16x16x32_bf16(ah, bh, acc, 0, 0, 0);
      acc = __builtin_amdgcn_mfma_f32_16x16x32_bf16(ah, bl, acc, 0, 0, 0);
      acc = __builtin_amdgcn_mfma_f32_16x16x32_bf16(al, bh, acc, 0, 0, 0);
    }
    __syncthreads();
  }
#pragma unroll
  for (int r = 0; r < 4; ++r) {
    int orow = i0 + wm * 16 + (lane >> 4) * 4 + r;
    int ocol = j0 + wn * 16 + r16;
    G[orow * 1024 + ocol] = __float2bfloat16(acc[r]);
  }
}

// ---------------- xWs = bf16((x·W)·invL) (4096x1024), 3-term hi/lo ----------
__global__ __launch_bounds__(256) void k_xw(const bf16_t* __restrict__ xh_,
                                            const bf16_t* __restrict__ xl_,
                                            const bf16_t* __restrict__ Bh_,
                                            const bf16_t* __restrict__ Bl_,
                                            const float* __restrict__ prm,
                                            bf16_t* __restrict__ out) {
  __shared__ __align__(16) ushort_t Axh[2][64 * 64], Axl[2][64 * 64],
                                    Bwh[2][64 * 64], Bwl[2][64 * 64];
  const int tid = threadIdx.x, lane = tid & 63, wave = tid >> 6;
  const int wm = wave >> 1, wn = wave & 1;
  const int m0 = blockIdx.x * 64, n0 = blockIdx.y * 64;
  const int r16 = lane & 15, kg = lane >> 4;

  auto stage = [&](int buf, int kt) {
#pragma unroll
    for (int q = 0; q < 2; ++q) {
      int lin = (tid + q * 256) * 8;
      int row = lin >> 6;
      int col = ((((lin >> 3) & 7) ^ (row & 7)) << 3);
      gload_lds16(xh_ + (long)(m0 + row) * 512 + kt + col, &Axh[buf][lin]);
      gload_lds16(xl_ + (long)(m0 + row) * 512 + kt + col, &Axl[buf][lin]);
      gload_lds16(Bh_ + (long)(n0 + row) * 512 + kt + col, &Bwh[buf][lin]);
      gload_lds16(Bl_ + (long)(n0 + row) * 512 + kt + col, &Bwl[buf][lin]);
    }
  };

  f32x4 acc[2][2] = {};
  stage(0, 0);
  __syncthreads();
  for (int t = 0; t < 8; ++t) {
    if (t + 1 < 8) stage((t + 1) & 1, (t + 1) * 64);
    const int b = t & 1;
#pragma unroll
    for (int kk = 0; kk < 64; kk += 32) {
      bf16x8 ah[2], al[2], bh[2], bl[2];
#pragma unroll
      for (int f = 0; f < 2; ++f) {
        int ra = wm * 32 + f * 16 + r16;
        int rb = wn * 32 + f * 16 + r16;
        int oa = ra * 64 + ((kk + kg * 8) ^ ((ra & 7) * 8));
        int ob = rb * 64 + ((kk + kg * 8) ^ ((rb & 7) * 8));
        ah[f] = *(const bf16x8*)&Axh[b][oa];
        al[f] = *(const bf16x8*)&Axl[b][oa];
        bh[f] = *(const bf16x8*)&Bwh[b][ob];
        bl[f] = *(const bf16x8*)&Bwl[b][ob];
      }
#pragma unroll
      for (int i = 0; i < 2; ++i)
#pragma unroll
        for (int j = 0; j < 2; ++j) {
          acc[i][j] = __builtin_amdgcn_mfma_f32_16x16x32_bf16(ah[i], bh[j], acc[i][j], 0, 0, 0);
          acc[i][j] = __builtin_amdgcn_mfma_f32_16x16x32_bf16(ah[i], bl[j], acc[i][j], 0, 0, 0);
          acc[i][j] = __builtin_amdgcn_mfma_f32_16x16x32_bf16(al[i], bh[j], acc[i][j], 0, 0, 0);
        }
    }
    __syncthreads();
  }
  const float invL = prm[21];
#pragma unroll
  for (int i = 0; i < 2; ++i)
#pragma unroll
    for (int j = 0; j < 2; ++j)
#pragma unroll
      for (int r = 0; r < 4; ++r) {
        int row = m0 + wm * 32 + i * 16 + (lane >> 4) * 4 + r;
        int col = n0 + wn * 32 + j * 16 + r16;
        out[(long)row * 1024 + col] = __float2bfloat16(acc[i][j][r] * invL);
      }
}

// ---------------- Rayleigh num/den partials ----------------
__global__ __launch_bounds__(256) void k_dot(const float* __restrict__ A0,
                                             const float* __restrict__ B,
                                             float* __restrict__ numP,
                                             float* __restrict__ denP) {
  __shared__ float redn[4], redd[4];
  const int tid = threadIdx.x;
  const int idx4 = blockIdx.x * 256 + tid;
  const f32x4 a = ((const f32x4*)A0)[idx4];
  const f32x4 b = ((const f32x4*)B)[idx4];
  float nv = a[0]*b[0] + a[1]*b[1] + a[2]*b[2] + a[3]*b[3];
  float dv = 0.0f;
#pragma unroll
  for (int q = 0; q < 4; ++q) {
    int i = idx4 * 4 + q;
    if ((i >> 9) == (i & 511)) dv += b[q];
  }
  for (int off = 32; off; off >>= 1) {
    nv += __shfl_down(nv, off, 64);
    dv += __shfl_down(dv, off, 64);
  }
  if ((tid & 63) == 0) { redn[tid >> 6] = nv; redd[tid >> 6] = dv; }
  __syncthreads();
  if (tid == 0) {
    numP[blockIdx.x] = redn[0] + redn[1] + redn[2] + redn[3];
    denP[blockIdx.x] = redd[0] + redd[1] + redd[2] + redd[3];
  }
}

__global__ __launch_bounds__(256) void k_setup(const float* __restrict__ alpha,
                                               const float* __restrict__ beta,
                                               const float* __restrict__ numP,
                                               const float* __restrict__ denP,
                                               float* __restrict__ params) {
  __shared__ float redn[4], redd[4];
  __shared__ float Lsh;
  const int tid = threadIdx.x;
  float nv = numP[tid], dv = denP[tid];
  for (int off = 32; off; off >>= 1) {
    nv += __shfl_down(nv, off, 64);
    dv += __shfl_down(dv, off, 64);
  }
  if ((tid & 63) == 0) { redn[tid >> 6] = nv; redd[tid >> 6] = dv; }
  __syncthreads();
  if (tid == 0)
    Lsh = (redn[0] + redn[1] + redn[2] + redn[3]) /
          (redd[0] + redd[1] + redd[2] + redd[3]);
  __syncthreads();
  const int t = tid;
  if (t >= 10) return;
  float L = Lsh;
  float invL = 1.0f / L;
  float lam = 0.001f * invL;
  const float* a = alpha + t * 20;
  float mx = a[0];
  for (int k = 1; k < 20; ++k) mx = fmaxf(mx, a[k]);
  float e[20], ssum = 0.0f;
  for (int k = 0; k < 20; ++k) { e[k] = expf(a[k] - mx); ssum += e[k]; }
  float inv = 1.0f / ssum;
  float* P = params + t * 32;
  for (int k = 0; k < 20; ++k) P[k] = e[k] * inv;
  float b0 = beta[t * 2], b1 = beta[t * 2 + 1];
  float bm = fmaxf(b0, b1);
  float eb0 = expf(b0 - bm), eb1 = expf(b1 - bm);
  float bw0 = eb0 / (eb0 + eb1);
  P[20] = ((float)(t + 1) / (float)(t + 4)) * bw0;  // c_{i+1} * bw0_i
  P[21] = invL;
  P[22] = lam;
  P[23] = L;
}

// ---------------- iteration 0: zaux=0 -> zg = xWs (pure elementwise) -----
__global__ __launch_bounds__(256) void k_it0(const bf16_t* __restrict__ xWs,
                                             bf16_t* __restrict__ zauxN,
                                             bf16_t* __restrict__ zB,
                                             const float* __restrict__ prm) {
  const long i = ((long)blockIdx.x * 256 + threadIdx.x) * 8;
  const float d = prm[20], lam = prm[22];
  float aw[20];
#pragma unroll
  for (int k = 0; k < 20; ++k) aw[k] = prm[k];
  bf16x8 v = *(const bf16x8*)(const void*)(xWs + i);
#pragma unroll
  for (int r = 0; r < 8; ++r) {
    float zop = act_mix((float)v[r], aw, lam);
    zB[i + r] = __float2bfloat16(zop);
    zauxN[i + r] = __float2bfloat16(zop * (1.0f + d));  // zold = 0
  }
}

// ---------------- main iteration: acc = zaux·G; epilogue -------------------
// zg = zaux + xWs - acc*invL; zop = mix(zg); zB=zop; zauxN=zop+d*(zop-zold).
// Round-6 lesson: in-block pipelining alone didn't help at 2 blocks/CU
// (occupancy ~20%, 746 GB/s). This round: 64x64 tile, grid 1024 = 4 blocks/CU,
// 32KB LDS, launch_bounds(256,4) -> ~16 waves/CU of TLP. Counted-vmcnt kept.
// zaux PING-PONGS (A=zx_in, zauxN=zx_out) - fixes the cross-block RW race on
// the GEMM operand that rounds 5/6 survived only by lockstep luck.
template <bool LAST>
__global__ __launch_bounds__(256, 4) void k_iter(const bf16_t* __restrict__ A,
                                                 const bf16_t* __restrict__ G,
                                                 const bf16_t* __restrict__ xWs,
                                                 bf16_t* __restrict__ zauxN,
                                                 bf16_t* zB, float* zio,
                                                 const float* __restrict__ prm) {
  __shared__ __align__(16) ushort_t As[2][64 * 64], Bs[2][64 * 64];
  const int tid = threadIdx.x, lane = tid & 63, wave = tid >> 6;
  const int wm = wave >> 1, wn = wave & 1;
  const int bid = blockIdx.x;
  const int swz = (bid & 7) * 128 + (bid >> 3);   // XCD swizzle (1024 % 8 == 0)
  const int m0 = (swz >> 4) * 64, n0 = (swz & 15) * 64;
  const int r16 = lane & 15, kg = lane >> 4;

  auto stage = [&](int buf, int kt) {             // exactly 4 gload_lds / thread
#pragma unroll
    for (int q = 0; q < 2; ++q) {
      int lin = (tid + q * 256) * 8;
      int row = lin >> 6;
      int col = ((((lin >> 3) & 7) ^ (row & 7)) << 3);
      gload_lds16(A + (long)(m0 + row) * 1024 + kt + col, &As[buf][lin]);
      gload_lds16(G + (long)(n0 + row) * 1024 + kt + col, &Bs[buf][lin]);
    }
  };

  f32x4 acc[2][2] = {};
  auto compute = [&](int b) {
#pragma unroll
    for (int kk = 0; kk < 64; kk += 32) {
      bf16x8 a[2], bb[2];
#pragma unroll
      for (int f = 0; f < 2; ++f) {
        int ra = wm * 32 + f * 16 + r16;
        int rb = wn * 32 + f * 16 + r16;
        a[f]  = *(const bf16x8*)&As[b][ra * 64 + ((kk + kg * 8) ^ ((ra & 7) * 8))];
        bb[f] = *(const bf16x8*)&Bs[b][rb * 64 + ((kk + kg * 8) ^ ((rb & 7) * 8))];
      }
#pragma unroll
      for (int i = 0; i < 2; ++i)
#pragma unroll
        for (int j = 0; j < 2; ++j)
          acc[i][j] = __builtin_amdgcn_mfma_f32_16x16x32_bf16(a[i], bb[j], acc[i][j], 0, 0, 0);
    }
  };

  stage(0, 0);
  stage(1, 64);
  asm volatile("s_waitcnt vmcnt(4)" ::: "memory");   // tile 0 landed (own)
  __builtin_amdgcn_s_barrier();                      // ...and by all waves
  __builtin_amdgcn_sched_barrier(0);

  for (int t = 0; t < 16; ++t) {
    compute(t & 1);
    if (t == 15) break;
    asm volatile("s_waitcnt lgkmcnt(0)" ::: "memory");
    __builtin_amdgcn_sched_barrier(0);
    __builtin_amdgcn_s_barrier();
    if (t + 2 < 16) {
      stage(t & 1, (t + 2) * 64);
      asm volatile("s_waitcnt vmcnt(4)" ::: "memory"); // tile t+1 done; t+2 in flight
    } else {
      asm volatile("s_waitcnt vmcnt(0)" ::: "memory");
    }
    __builtin_amdgcn_s_barrier();
    __builtin_amdgcn_sched_barrier(0);
  }
  __builtin_amdgcn_sched_barrier(0);

  const float d_i = prm[20];
  const float invL = prm[21];
  const float lam = prm[22];
  float aw[20];
#pragma unroll
  for (int k = 0; k < 20; ++k) aw[k] = prm[k];

  // epilogue: issue all operand loads first (ILP), then compute+store
  float xv[2][2][4], av[2][2][4], zv[2][2][4];
#pragma unroll
  for (int i = 0; i < 2; ++i)
#pragma unroll
    for (int j = 0; j < 2; ++j)
#pragma unroll
      for (int r = 0; r < 4; ++r) {
        int row = m0 + wm * 32 + i * 16 + (lane >> 4) * 4 + r;
        int col = n0 + wn * 32 + j * 16 + r16;
        long idx = (long)row * 1024 + col;
        xv[i][j][r] = __bfloat162float(xWs[idx]);
        av[i][j][r] = __bfloat162float(A[idx]);
        if (!LAST) zv[i][j][r] = __bfloat162float(zB[idx]);
      }
#pragma unroll
  for (int i = 0; i < 2; ++i)
#pragma unroll
    for (int j = 0; j < 2; ++j)
#pragma unroll
      for (int r = 0; r < 4; ++r) {
        int row = m0 + wm * 32 + i * 16 + (lane >> 4) * 4 + r;
        int col = n0 + wn * 32 + j * 16 + r16;
        long idx = (long)row * 1024 + col;
        float zg = fmaf(-acc[i][j][r], invL, av[i][j][r] + xv[i][j][r]);
        float zop = act_mix(zg, aw, lam);
        if (LAST) {
          zio[idx] = zop;
        } else {
          zB[idx] = __float2bfloat16(zop);
          zauxN[idx] = __float2bfloat16(fmaf(d_i, zop - zv[i][j][r], zop));
        }
      }
}

// ---------------- orchestration ----------------
extern "C" void kernel_launch(void* const* d_in, const int* in_sizes, int n_in,
                              void* d_out, int out_size, void* d_ws, size_t ws_size,
                              hipStream_t stream) {
  const float* x     = (const float*)d_in[0];
  const float* W     = (const float*)d_in[1];
  const float* alpha = (const float*)d_in[2];
  const float* beta  = (const float*)d_in[3];
  float* zout = (float*)d_out;

  char* ws = (char*)d_ws;
  const size_t MB = 1u << 20;
  float* pb[11];
  for (int k = 0; k < 11; ++k) pb[k] = (float*)(ws + (size_t)k * 1024);
  float* numP   = (float*)(ws + 12 * 1024);
  float* denP   = (float*)(ws + 13 * 1024);
  float* params = (float*)(ws + 14 * 1024);
  const size_t HDR = 32768;
  float*  A0f  = (float*)(ws + HDR);                 // 1 MB
  float*  Bf   = (float*)(ws + HDR + 1 * MB);        // 1 MB
  bf16_t* H0   = (bf16_t*)(ws + HDR + 2 * MB);       // 0.5 MB
  bf16_t* L0   = (bf16_t*)(ws + HDR + 2 * MB + 512 * 1024);
  bf16_t* H1   = (bf16_t*)(ws + HDR + 3 * MB);
  bf16_t* L1   = (bf16_t*)(ws + HDR + 3 * MB + 512 * 1024);
  bf16_t* Whi  = (bf16_t*)(ws + HDR + 4 * MB);       // 1 MB
  bf16_t* Wlo  = (bf16_t*)(ws + HDR + 5 * MB);       // 1 MB
  bf16_t* Wth  = (bf16_t*)(ws + HDR + 6 * MB);       // 1 MB
  bf16_t* Wtl  = (bf16_t*)(ws + HDR + 7 * MB);       // 1 MB
  bf16_t* Gm   = (bf16_t*)(ws + HDR + 8 * MB);       // 2 MB
  bf16_t* xh   = (bf16_t*)(ws + HDR + 10 * MB);      // 4 MB
  bf16_t* xl   = (bf16_t*)(ws + HDR + 14 * MB);      // 4 MB
  bf16_t* xWs  = (bf16_t*)(ws + HDR + 18 * MB);      // 8 MB (bf16, pre-scaled by invL)
  bf16_t* zx0  = (bf16_t*)(ws + HDR + 26 * MB);      // 8 MB (zaux ping)
  bf16_t* zx1  = (bf16_t*)(ws + HDR + 34 * MB);      // 8 MB (zaux pong)
  bf16_t* zB   = (bf16_t*)(ws + HDR + 42 * MB);      // 8 MB (z storage)

  k_prep<<<10240, 256, 0, stream>>>(W, x, Whi, Wlo, Wth, Wtl, xh, xl);

  // L: A0 = W*W^T (hi/lo MFMA), 9 normalized squarings, Rayleigh via traces
  k_sqm<1024, true, true><<<dim3(16, 16), 256, 0, stream>>>(
      Whi, Wlo, H0, L0, A0f, nullptr, pb[0]);
  bf16_t* Hs[2] = {H0, H1};
  bf16_t* Ls[2] = {L0, L1};
  int pp = 0;
  for (int k = 0; k < 9; ++k) {
    if (k == 8)
      k_sqm<512, false, true><<<dim3(16, 16), 256, 0, stream>>>(
          Hs[pp], Ls[pp], Hs[pp ^ 1], Ls[pp ^ 1], Bf, pb[k], pb[k + 1]);
    else
      k_sqm<512, false, false><<<dim3(16, 16), 256, 0, stream>>>(
          Hs[pp], Ls[pp], Hs[pp ^ 1], Ls[pp ^ 1], nullptr, pb[k], pb[k + 1]);
    pp ^= 1;
  }
  k_dot<<<256, 256, 0, stream>>>(A0f, Bf, numP, denP);
  k_setup<<<1, 256, 0, stream>>>(alpha, beta, numP, denP, params);

  // G (L-independent); xWs needs invL -> after k_setup
  k_G<<<dim3(32, 32), 256, 0, stream>>>(Wth, Wtl, Gm);
  k_xw<<<dim3(64, 16), 256, 0, stream>>>(xh, xl, Wth, Wtl, params, xWs);

  // iter 0 (zaux = 0): pure elementwise, writes zaux_1 into zx1
  k_it0<<<2048, 256, 0, stream>>>(xWs, zx1, zB, params);

  // iters 1..9: zaux ping-pong; iter i reads zx[i&1], writes zx[(i+1)&1]
  bf16_t* zx[2] = {zx0, zx1};
  for (int i = 1; i < 9; ++i)
    k_iter<false><<<1024, 256, 0, stream>>>(zx[i & 1], Gm, xWs, zx[(i + 1) & 1],
                                            zB, zout, params + i * 32);
  k_iter<true><<<1024, 256, 0, stream>>>(zx[9 & 1], Gm, xWs, zx0 /*unused*/,
                                         zB, zout, params + 9 * 32);
}